// Round 10
// baseline (1337.105 us; speedup 1.0000x reference)
//
#include <hip/hip_runtime.h>
#include <hip/hip_bf16.h>
#include <math.h>

typedef __hip_bfloat16 bf16;

#define LRELU(v) ((v) >= 0.f ? (v) : 0.2f * (v))

__device__ __forceinline__ float b2f(bf16 v) { return __bfloat162float(v); }
__device__ __forceinline__ bf16 f2b(float v) { return __float2bfloat16(v); }

__device__ __forceinline__ float eload(const void* p, long i, int isf32)
{
    return isf32 ? ((const float*)p)[i] : b2f(((const bf16*)p)[i]);
}

union BfPack { short4 s; bf16 h[4]; };
typedef __attribute__((ext_vector_type(8))) short bfrag_t;   // 8 bf16
typedef __attribute__((ext_vector_type(4))) float ffrag_t;   // 4 f32 acc
union PackU { bfrag_t v; bf16 b[8]; };

// ---------------------------------------------------------------------------
__global__ void dtype_detect_kernel(const void* probe, int n, int* flag)
{
    if (threadIdx.x == 0 && blockIdx.x == 0) {
        const bf16* e = (const bf16*)probe;
        int f32 = 0;
        for (int i = 0; i < n; ++i) {
            const float v = b2f(e[i]);
            if (!(v > -1.0f && v < 1.0f)) f32 = 1;
        }
        *flag = f32;
    }
}

// planar external [b0+b][C][HW] -> NHWC8 bf16 [b][C/8][HW][8]
__global__ void __launch_bounds__(256)
to_nhwc8_kernel(const void* __restrict__ src, const int* __restrict__ dflag,
                bf16* __restrict__ out, int b_off, int C, int HW, long n)
{
    const int ef = dflag[0];
    const int CG = C >> 3;
    for (long i = (long)blockIdx.x * 256 + threadIdx.x; i < n;
         i += (long)gridDim.x * 256) {
        const int c8 = (int)(i & 7);
        long r = i >> 3;
        const int p = (int)(r % HW); r /= HW;
        const int cg = (int)(r % CG);
        const int b = (int)(r / CG);
        out[i] = f2b(eload(src, ((long)(b_off + b) * C + cg * 8 + c8) * HW + p, ef));
    }
}

// xs(NHWC8) = x0(NHWC8) + ns * noise(planar ext), C=64, HW=4096
__global__ void __launch_bounds__(256)
addnoise_kernel(const bf16* __restrict__ x0, const void* __restrict__ noise,
                const void* __restrict__ ns_ptr, const int* __restrict__ dflag,
                bf16* __restrict__ out, int b_off, long n)
{
    const int ef = dflag[0];
    const float ns = eload(ns_ptr, 0, ef);
    for (long i = (long)blockIdx.x * 256 + threadIdx.x; i < n;
         i += (long)gridDim.x * 256) {
        const int c8 = (int)(i & 7);
        long r = i >> 3;
        const int p = (int)(r % 4096); r /= 4096;
        const int cg = (int)(r % 8);
        const int b = (int)(r / 8);
        out[i] = f2b(b2f(x0[i]) +
                     ns * eload(noise, ((long)(b_off + b) * 64 + cg * 8 + c8) * 4096 + p, ef));
    }
}

// ---------------------------------------------------------------------------
// single-launch weight prep: external [t][co][ci][3][3] ->
//   wp[t][cog][cc][tap][...] bf16, A-fragment-ready, zero-pad co.
// Intra-tap layout is LANE-LINEAR for conflict-free ds_read_b128:
//   element A[co][ci] at position co*8 + (ci>>3)*128 + (ci&7)
// so lane l=16q+n (reading co=n, ci=q*8..q*8+7 at offset q*128+n*8) maps to
// slot l -> a wave reads 1024 contiguous bytes (banking floor, 0 conflicts).
// ---------------------------------------------------------------------------
struct WEnt { const void* src; long dst_off; long total; int Cout; int Cin; };
struct WTab { WEnt e[17]; int n; };

__global__ void __launch_bounds__(256)
wprep_all_kernel(WTab tab, const int* __restrict__ dflag, bf16* __restrict__ out)
{
    const int ef = dflag[0];
    for (int k = 0; k < tab.n; ++k) {
        const WEnt E = tab.e[k];
        const int cogs = (E.Cout + 15) >> 4, ccs = E.Cin >> 5;
        const long src_t = (long)E.Cout * E.Cin * 9;
        for (long i = (long)blockIdx.x * 256 + threadIdx.x; i < E.total;
             i += (long)gridDim.x * 256) {
            const int e = (int)(i & 511);
            long r = i >> 9;
            const int tap = (int)(r % 9); r /= 9;
            const int cc = (int)(r % ccs); r /= ccs;
            const int cog = (int)(r % cogs);
            const int t = (int)(r / cogs);
            const int nn = (e >> 3) & 15;            // co (lane-linear layout)
            const int kk = (e >> 7) * 8 + (e & 7);   // ci
            const int co = cog * 16 + nn, ci = cc * 32 + kk;
            float v = 0.f;
            if (co < E.Cout)
                v = eload(E.src, (long)t * src_t + ((long)co * E.Cin + ci) * 9 + tap, ef);
            out[E.dst_off + i] = f2b(v);
        }
    }
}

// ---------------------------------------------------------------------------
// MFMA implicit-GEMM 3x3 conv, NHWC8 src, prepped weights.
// Tile 16x16 px; block handles CPB consecutive cogs (CPB | cogs guaranteed).
// CPB<=3 (48 AGPR) + __launch_bounds__(256,4).
// XCD-aware bijective block swizzle (T1/m204): bid = x*q + min(x,r) + (d>>3).
// Weight fragments staged in LDS (sW) cooperatively per chunk, with:
//  - lane-linear fragment layout (see wprep) -> conflict-free sW ds_reads
//    (R9's [co16][ci32] layout was 8-way conflicted: +3.5M conflict cycles);
//  - hoisted staging descriptors: sW dst is LINEAR (g*8); src offset
//    g*8 + c*(wc_cstride-4608) precomputed once (no div-by-576 in the loop,
//    which was R9's VALUBusy 29->40% regression).
// Src staging: reg path, fused load->ds_write per granule, hoisted
// descriptors. OOB halo zeroed once in prologue.
// img_per_t>0: per-image-group weights (merged branches), weight idx = b/img_per_t.
// src_bmod>0: src image index = b % src_bmod (shared-input merged conv).
// dst_kind: 0=NHWC8 bf16 (+act), 1=NHWC8 f32 += (v*es[e]+eb[e])*att,
//           2=NHWC8 bf16 resid + lrelu(v)*es[0], 3=planar f32 (+act).
// ---------------------------------------------------------------------------
template <int CPB>
__global__ void __launch_bounds__(256, 4)
conv_mfma(const bf16* __restrict__ src,
          const bf16* __restrict__ wp,
          const void* __restrict__ bias,
          void* __restrict__ dst, int dst_kind, int act,
          const bf16* __restrict__ resid,
          const float* __restrict__ att,
          const void* __restrict__ es_ptr, const void* __restrict__ eb_ptr,
          int e_idx,
          const int* __restrict__ dflag,
          int B, int Cin, int Cout, int H, int W, int up,
          int cog_blocks,
          int src_row0, int src_rows, int dst_row0, int dst_rows_buf,
          int dst_y0, int dst_rows,
          int img_per_t, long wstride, int src_bmod)
{
    __shared__ __align__(16) bf16 sI[324 * 32];      // 20,736 B
    __shared__ __align__(16) bf16 sW[CPB * 4608];    // 9,216 B per cog

    const int ef = dflag[0];
    const int ccs  = Cin >> 5;
    const int CGi = Cin >> 3;
    const int CGo = Cout >> 3;
    const int tilesX = W >> 4;
    const int tilesY = dst_rows >> 4;
    const int inW = up ? (W >> 1) : W;

    // ---- XCD-aware bijective remap (m204, simplified chunk-start form) ----
    int bid;
    {
        const unsigned d = blockIdx.x, nwg = gridDim.x;
        const unsigned qq = nwg >> 3, rr = nwg & 7;
        const unsigned x = d & 7;
        bid = (int)(x * qq + (x < rr ? x : rr) + (d >> 3));
    }
    const int cogb = bid % cog_blocks; bid /= cog_blocks;
    const int tx = bid % tilesX; bid /= tilesX;
    const int ty = bid % tilesY;
    const int b  = bid / tilesY;
    const int cog0 = cogb * CPB;
    const int sbi = src_bmod ? (b % src_bmod) : b;
    const bf16* wpb = wp + (img_per_t ? (long)(b / img_per_t) * wstride : 0);

    const int tid = threadIdx.x;
    const int wave = tid >> 6, lane = tid & 63;
    const int n = lane & 15, q = lane >> 4;
    const int yb = dst_y0 + ty * 16, xb = tx * 16;
    const int r0w = wave * 4;

    int cb[3];
#pragma unroll
    for (int d = 0; d < 3; ++d) {
        const int tc = n + d;
        cb[d] = tc * 32 + ((q ^ ((tc >> 1) & 3)) << 3);
    }

    // ---- hoisted src staging descriptors (constant across cc chunks) ----
    unsigned gofs[6];            // element offset at cc=0 (valid iff vmask bit)
    int      lofs[6];            // LDS element offset (swizzled)
    unsigned vmask = 0;
    const unsigned ccstep = (unsigned)((4 * src_rows * inW) << 3);
#pragma unroll
    for (int k = 0; k < 6; ++k) {
        gofs[k] = 0; lofs[k] = 0;
        const int i = tid + k * 256;
        if (i < 1296) {
            const int pc = i % 324;
            const int cig = i / 324;
            const int trow = pc / 18, tcol = pc - trow * 18;
            lofs[k] = pc * 32 + ((cig ^ ((tcol >> 1) & 3)) << 3);
            const int iy = yb + trow - 1, ix = xb + tcol - 1;
            if (iy >= 0 && iy < H && ix >= 0 && ix < W) {
                const int sy = up ? (iy >> 1) : iy;
                const int sx = up ? (ix >> 1) : ix;
                gofs[k] = (unsigned)(((((long)sbi * CGi + cig) * src_rows
                                      + (sy - src_row0)) * inW + sx) << 3);
                vmask |= 1u << k;
            }
        }
    }

    // ---- hoisted weight staging descriptors (divisions once, not per cc) ----
    const long wc_cstride = (long)ccs * 4608;   // per-cog stride in wp
    unsigned wofs[7];
#pragma unroll
    for (int k = 0; k < 7; ++k) {
        wofs[k] = 0;
        const int g = tid + k * 256;
        if (g < CPB * 576) {
            const int c = g / 576;
            wofs[k] = (unsigned)((long)g * 8 + (long)c * (wc_cstride - 4608));
        }
    }

    // ---- one-time zero of OOB halo slots (never rewritten) ----
    {
        PackU z;
#pragma unroll
        for (int j = 0; j < 8; ++j) z.b[j] = f2b(0.0f);
#pragma unroll
        for (int k = 0; k < 6; ++k)
            if ((tid + k * 256 < 1296) && !(vmask & (1u << k)))
                *(bfrag_t*)&sI[lofs[k]] = z.v;
    }

    ffrag_t acc[CPB][4];
#pragma unroll
    for (int c = 0; c < CPB; ++c)
#pragma unroll
        for (int g = 0; g < 4; ++g) acc[c][g] = (ffrag_t){0.f, 0.f, 0.f, 0.f};

    const bf16* wsrc = wpb + (long)cog0 * ccs * 4608;

    for (int cc = 0; cc < ccs; ++cc) {
        // ---- stage src chunk cc: fused load->write per granule ----
#pragma unroll
        for (int k = 0; k < 6; ++k) {
            if (vmask & (1u << k)) {
                const bfrag_t v = *(const bfrag_t*)&src[gofs[k]];
                *(bfrag_t*)&sI[lofs[k]] = v;
                gofs[k] += ccstep;
            }
        }
        // ---- stage weight fragments (linear dst, precomputed src offs) ----
#pragma unroll
        for (int k = 0; k < 7; ++k) {
            const int g = tid + k * 256;
            if (g < CPB * 576) {
                const bfrag_t w = *(const bfrag_t*)&wsrc[wofs[k]];
                *(bfrag_t*)&sW[g * 8] = w;
            }
        }
        wsrc += 4608;
        __syncthreads();

        // ---- compute: pure LDS + MFMA, conflict-free sW reads ----
#pragma unroll
        for (int dx = 0; dx < 3; ++dx) {
            bfrag_t bcol[6];
#pragma unroll
            for (int rr = 0; rr < 6; ++rr)
                bcol[rr] = *(const bfrag_t*)&sI[(r0w + rr) * 18 * 32 + cb[dx]];
#pragma unroll
            for (int c = 0; c < CPB; ++c) {
                const bf16* wbase = &sW[c * 4608 + q * 128 + n * 8];
#pragma unroll
                for (int dy = 0; dy < 3; ++dy) {
                    const bfrag_t a = *(const bfrag_t*)&wbase[(dy * 3 + dx) * 512];
#pragma unroll
                    for (int g = 0; g < 4; ++g)
                        acc[c][g] = __builtin_amdgcn_mfma_f32_16x16x32_bf16(
                            a, bcol[g + dy], acc[c][g], 0, 0, 0);
                }
            }
        }
        __syncthreads();
    }

    // ---- epilogue ----
    const float es  = es_ptr ? eload(es_ptr, e_idx, ef) : 1.0f;
    const float ebv = eb_ptr ? eload(eb_ptr, e_idx, ef) : 0.0f;
    const int x = xb + n;
#pragma unroll
    for (int c = 0; c < CPB; ++c) {
        const int cog = cog0 + c;
        if (dst_kind == 3) {
#pragma unroll
            for (int g = 0; g < 4; ++g) {
                const int y = yb + r0w + g, yr = y - dst_row0;
#pragma unroll
                for (int reg = 0; reg < 4; ++reg) {
                    const int co = cog * 16 + q * 4 + reg;
                    if (co < Cout) {
                        float v = acc[c][g][reg];
                        if (bias) v += eload(bias, co, ef);
                        if (act) v = LRELU(v);
                        ((float*)dst)[(((long)b * Cout + co) * dst_rows_buf + yr) * W + x] = v;
                    }
                }
            }
            continue;
        }
        const int cg = cog * 2 + (q >> 1);
        const int c8 = (q & 1) * 4;
        float bv[4];
#pragma unroll
        for (int reg = 0; reg < 4; ++reg)
            bv[reg] = bias ? eload(bias, cog * 16 + q * 4 + reg, ef) : 0.0f;
#pragma unroll
        for (int g = 0; g < 4; ++g) {
            const int y = yb + r0w + g, yr = y - dst_row0;
            const long base = ((((long)b * CGo + cg) * dst_rows_buf + yr) * W + x) * 8 + c8;
            if (dst_kind == 0) {
                BfPack o;
#pragma unroll
                for (int reg = 0; reg < 4; ++reg) {
                    float v = acc[c][g][reg] + bv[reg];
                    if (act) v = LRELU(v);
                    o.h[reg] = f2b(v);
                }
                *(short4*)&((bf16*)dst)[base] = o.s;
            } else if (dst_kind == 1) {
                const float attv = att[(((long)b * 8 + e_idx) * H + y) * W + x];
                float* dp = (float*)dst + base;
                float4 dv = *(float4*)dp;
                dv.x += ((acc[c][g][0] + bv[0]) * es + ebv) * attv;
                dv.y += ((acc[c][g][1] + bv[1]) * es + ebv) * attv;
                dv.z += ((acc[c][g][2] + bv[2]) * es + ebv) * attv;
                dv.w += ((acc[c][g][3] + bv[3]) * es + ebv) * attv;
                *(float4*)dp = dv;
            } else {
                BfPack rv; rv.s = *(const short4*)&resid[base];
                BfPack o;
#pragma unroll
                for (int reg = 0; reg < 4; ++reg) {
                    const float v = acc[c][g][reg] + bv[reg];
                    o.h[reg] = f2b(b2f(rv.h[reg]) + LRELU(v) * es);
                }
                *(short4*)&((bf16*)dst)[base] = o.s;
            }
        }
    }
}

// ---------------------------------------------------------------------------
// ACC (+)= sum_t (xf[t] * tscale[t] + tbias[t]) * att[b,t,:]
// xf: NHWC8 bf16, images [ti*bc + b]; ACC: NHWC8 f32 over bc images.
// ---------------------------------------------------------------------------
__global__ void __launch_bounds__(256)
acc_att_kernel(const bf16* __restrict__ xf, const float* __restrict__ att,
               const void* __restrict__ ts, const void* __restrict__ tb,
               const int* __restrict__ dflag, float* __restrict__ ACC,
               int bc, int tcap, int tgrp, int init, long n)
{
    const int ef = dflag[0];
    for (long i = (long)blockIdx.x * 256 + threadIdx.x; i < n;
         i += (long)gridDim.x * 256) {
        long r = i >> 3;
        const int p = (int)(r % 4096); r /= 4096;
        r /= 8;                         // skip cg
        const int b = (int)r;
        float s = init ? 0.f : ACC[i];
        for (int ti = 0; ti < tcap; ++ti) {
            const int t = tgrp + ti;
            const float a = att[((long)b * 8 + t) * 4096 + p];
            const float v = b2f(xf[(long)ti * bc * 262144 + i]);
            s += (v * eload(ts, t, ef) + eload(tb, t, ef)) * a;
        }
        ACC[i] = s;
    }
}

// ---------------------------------------------------------------------------
// init conv: planar ext x [b0+b][3][64][64] -> NHWC8 x0, Cout=64
// ---------------------------------------------------------------------------
__global__ void __launch_bounds__(256)
conv_init_kernel(const void* __restrict__ src, const void* __restrict__ wgt,
                 const void* __restrict__ bias, bf16* __restrict__ dst,
                 const int* __restrict__ dflag, int b_off, int B)
{
    __shared__ float slds[3 * 34 * 36];
    __shared__ float wlds[3 * 16 * 12];
    const int ef = dflag[0];

    int bid = blockIdx.x;
    const int coI = bid & 3; bid >>= 2;
    const int tx = bid & 1; bid >>= 1;
    const int ty = bid & 1; bid >>= 1;
    const int b = bid;
    const int co0 = coI * 16;
    const int tid = threadIdx.x;
    const int wave = tid >> 6, lane = tid & 63;
    const int ty4 = lane >> 3, tx4 = lane & 7;
    const int yb = ty * 32, xb = tx * 32;

    for (int i = tid; i < 34 * 34 * 3; i += 256) {
        const int c = i / 1156, p = i % 1156;
        const int row = p / 34, col = p % 34;
        const int iy = yb + row - 1, ix = xb + col - 1;
        float v = 0.f;
        if (iy >= 0 && iy < 64 && ix >= 0 && ix < 64)
            v = eload(src, ((long)(b_off + b) * 3 + c) * 4096 + iy * 64 + ix, ef);
        slds[(c * 34 + row) * 36 + col] = v;
    }
    for (int i = tid; i < 3 * 144; i += 256) {
        const int ci = i / 144, r = i % 144;
        const int co = r / 9, k = r % 9;
        wlds[(ci * 16 + co) * 12 + k] = eload(wgt, ((long)(co0 + co) * 3 + ci) * 9 + k, ef);
    }
    __syncthreads();

    float acc[4][16];
#pragma unroll
    for (int i = 0; i < 4; ++i)
#pragma unroll
        for (int j = 0; j < 16; ++j) acc[i][j] = 0.f;

    for (int ci = 0; ci < 3; ++ci) {
        float in[6][6];
        const float* sp = &slds[(ci * 34 + ty4 * 4) * 36 + tx4 * 4];
#pragma unroll
        for (int r = 0; r < 6; ++r) {
            const float4 v4 = *(const float4*)(sp + r * 36);
            const float2 v2 = *(const float2*)(sp + r * 36 + 4);
            in[r][0] = v4.x; in[r][1] = v4.y; in[r][2] = v4.z; in[r][3] = v4.w;
            in[r][4] = v2.x; in[r][5] = v2.y;
        }
#pragma unroll
        for (int cc = 0; cc < 4; ++cc) {
            const float* wp = &wlds[(ci * 16 + wave * 4 + cc) * 12];
            const float4 wa = *(const float4*)wp;
            const float4 wb = *(const float4*)(wp + 4);
            const float w8 = wp[8];
#pragma unroll
            for (int r = 0; r < 4; ++r)
#pragma unroll
                for (int c = 0; c < 4; ++c)
                    acc[cc][r * 4 + c] += in[r][c] * wa.x + in[r][c+1] * wa.y + in[r][c+2] * wa.z
                        + in[r+1][c] * wa.w + in[r+1][c+1] * wb.x + in[r+1][c+2] * wb.y
                        + in[r+2][c] * wb.z + in[r+2][c+1] * wb.w + in[r+2][c+2] * w8;
        }
    }

    const int cg = coI * 2 + (wave >> 1);
    const int c8 = (wave & 1) * 4;
    float bv[4];
#pragma unroll
    for (int cc = 0; cc < 4; ++cc)
        bv[cc] = bias ? eload(bias, co0 + wave * 4 + cc, ef) : 0.0f;
#pragma unroll
    for (int r = 0; r < 4; ++r) {
        const int y = yb + ty4 * 4 + r;
#pragma unroll
        for (int c = 0; c < 4; ++c) {
            const int x = xb + tx4 * 4 + c;
            BfPack o;
#pragma unroll
            for (int cc = 0; cc < 4; ++cc)
                o.h[cc] = f2b(acc[cc][r * 4 + c] + bv[cc]);
            *(short4*)&dst[((((long)b * 8 + cg) * 64 + y) * 64 + x) * 8 + c8] = o.s;
        }
    }
}

// ---------------------------------------------------------------------------
__global__ void __launch_bounds__(256)
gn_silu_kernel(bf16* __restrict__ d, const void* __restrict__ g,
               const void* __restrict__ be, const int* __restrict__ dflag,
               int C, int gsize, int HW)
{
    const int ef = dflag[0];
    const int groups = C / gsize;
    const int blk = blockIdx.x;
    const int b  = blk / groups;
    const int gr = blk % groups;
    const long base = ((long)b * (C >> 3) + (long)gr * (gsize >> 3)) * HW * 8;
    const int N = gsize * HW;

    float s = 0.0f, ss = 0.0f;
    for (int i = threadIdx.x; i < N; i += 256) {
        const float v = b2f(d[base + i]);
        s += v; ss += v * v;
    }
    __shared__ float rs[256], rss[256];
    rs[threadIdx.x] = s; rss[threadIdx.x] = ss;
    __syncthreads();
    for (int o = 128; o > 0; o >>= 1) {
        if (threadIdx.x < o) {
            rs[threadIdx.x]  += rs[threadIdx.x + o];
            rss[threadIdx.x] += rss[threadIdx.x + o];
        }
        __syncthreads();
    }
    __shared__ float mean_s, inv_s;
    if (threadIdx.x == 0) {
        const float mean = rs[0] / (float)N;
        const float var  = rss[0] / (float)N - mean * mean;
        mean_s = mean; inv_s = rsqrtf(var + 1e-5f);
    }
    __syncthreads();
    const float mean = mean_s, inv = inv_s;
    for (int i = threadIdx.x; i < N; i += 256) {
        const int c = gr * gsize + (i / (HW * 8)) * 8 + (i & 7);
        const float v  = b2f(d[base + i]);
        const float xn = (v - mean) * inv * eload(g, c, ef) + eload(be, c, ef);
        d[base + i] = f2b(xn / (1.0f + expf(-xn)));
    }
}

__global__ void __launch_bounds__(256)
softmax_t_kernel(float* __restrict__ m, int BHW, int HW, float invtemp)
{
    const int i = blockIdx.x * 256 + threadIdx.x;
    if (i >= BHW) return;
    const int b = i / HW;
    const int p = i % HW;
    const long base = (long)b * 8 * HW + p;
    float v[8];
    float mx = -1e30f;
#pragma unroll
    for (int t = 0; t < 8; ++t) {
        v[t] = m[base + (long)t * HW] * invtemp;
        mx = fmaxf(mx, v[t]);
    }
    float s = 0.0f;
#pragma unroll
    for (int t = 0; t < 8; ++t) { v[t] = expf(v[t] - mx); s += v[t]; }
    const float r = 1.0f / s;
#pragma unroll
    for (int t = 0; t < 8; ++t) m[base + (long)t * HW] = v[t] * r;
}

__global__ void __launch_bounds__(256)
combine_kernel(const bf16* __restrict__ x0, const float* __restrict__ acc,
               const void* __restrict__ ss, const int* __restrict__ dflag,
               bf16* __restrict__ out, long n)
{
    const long i = (long)blockIdx.x * 256 + threadIdx.x;
    if (i < n) out[i] = f2b(b2f(x0[i]) + acc[i] * eload(ss, 0, dflag[0]));
}

__global__ void __launch_bounds__(256)
zero_kernel(float* __restrict__ p, long n)
{
    const long i = (long)blockIdx.x * 256 + threadIdx.x;
    if (i < n) p[i] = 0.0f;
}

// ---------------------------------------------------------------------------
static const int* g_dflag;

static void conv2w(hipStream_t st, const bf16* src, const bf16* wp,
                   const void* bias, void* dst, int dst_kind, int act,
                   int B, int Cin, int Cout, int H, int W, int up,
                   int src_row0, int src_rows, int dst_row0, int dst_rows_buf,
                   int dst_y0, int dst_rows,
                   const bf16* resid = nullptr, const float* att = nullptr,
                   const void* es = nullptr, const void* eb = nullptr, int eidx = 0,
                   int img_per_t = 0, long wstride = 0, int src_bmod = 0)
{
    const int cogs = (Cout + 15) >> 4;
    const int spatial = B * (dst_rows >> 4) * (W >> 4);
    // CPB: largest divisor of cogs (<=3, 48 AGPR cap) whose block count
    // fills residency (>=1024); else 1.
    static const int cands[3] = {3, 2, 1};
    int cpb = 1;
    for (int k = 0; k < 3; ++k) {
        const int c = cands[k];
        if (cogs % c) continue;
        if ((long)spatial * (cogs / c) >= 1024) { cpb = c; break; }
        if (c == 1) cpb = 1;   // tiny spatial: max blocks, L2 eats restaging
    }
    const int cogb = cogs / cpb;
    const int blocks = spatial * cogb;
#define LAUNCH(CP) conv_mfma<CP><<<blocks, 256, 0, st>>>( \
        src, wp, bias, dst, dst_kind, act, resid, att, es, eb, eidx, g_dflag, \
        B, Cin, Cout, H, W, up, cogb, \
        src_row0, src_rows, dst_row0, dst_rows_buf, dst_y0, dst_rows, \
        img_per_t, wstride, src_bmod)
    switch (cpb) {
        case 3: LAUNCH(3); break;
        case 2: LAUNCH(2); break;
        default: LAUNCH(1); break;
    }
#undef LAUNCH
}

static void conv2(hipStream_t st, const bf16* src, const bf16* wp,
                  const void* bias, void* dst, int dst_kind, int act,
                  int B, int Cin, int Cout, int H, int W, int up,
                  const bf16* resid = nullptr, const float* att = nullptr,
                  const void* es = nullptr, const void* eb = nullptr, int eidx = 0,
                  int img_per_t = 0, long wstride = 0, int src_bmod = 0)
{
    conv2w(st, src, wp, bias, dst, dst_kind, act, B, Cin, Cout, H, W, up,
           0, up ? (H >> 1) : H, 0, H, 0, H, resid, att, es, eb, eidx,
           img_per_t, wstride, src_bmod);
}

static long wp_elems(int T, int Cout, int Cin)
{
    return (long)T * ((Cout + 15) / 16) * (Cin / 32) * 9 * 512;
}

extern "C" void kernel_launch(void* const* d_in, const int* in_sizes, int n_in,
                              void* d_out, int out_size, void* d_ws, size_t ws_size,
                              hipStream_t stream)
{
    const void* x_all   = d_in[0];
    const void* sp_all  = d_in[1];
    const void* nz_all  = d_in[2];
    const void* init_w  = d_in[3];
    const void* init_b  = d_in[4];
    const void* pre_w   = d_in[5];
    const void* tw0     = d_in[6];
    const void* tw1     = d_in[7];
    const void* tw2     = d_in[8];
    const void* tw3     = d_in[9];
    const void* tscale  = d_in[10];
    const void* tbias   = d_in[11];
    const void* nscale  = d_in[12];
    const void* sscale  = d_in[13];
    const void* pscale  = d_in[14];
    const void* post_w  = d_in[15];
    const void* post_b  = d_in[16];
    const void* m1_w    = d_in[17];
    const void* m1_b    = d_in[18];
    const void* m1_g    = d_in[19];
    const void* m1_be   = d_in[20];
    const void* m2_w    = d_in[21];
    const void* m2_g    = d_in[22];
    const void* m2_be   = d_in[23];
    const void* u1a_w   = d_in[24];
    const void* u1b_w   = d_in[25];
    const void* u1b_g   = d_in[26];
    const void* u1b_be  = d_in[27];
    const void* u2a_w   = d_in[28];
    const void* u2b_w   = d_in[29];
    const void* u2b_g   = d_in[30];
    const void* u2b_be  = d_in[31];
    const void* mf_w    = d_in[32];
    const void* up1_w   = d_in[33];
    const void* up1_b   = d_in[34];
    const void* up2_w   = d_in[35];
    const void* up2_b   = d_in[36];
    const void* hr_w    = d_in[37];
    const void* hr_b    = d_in[38];
    const void* fin_w   = d_in[39];
    const void* fin_b   = d_in[40];
    (void)in_sizes; (void)n_in; (void)out_size;

    char* wsb = (char*)d_ws;
    int* dflag = (int*)wsb;
    g_dflag = dflag;
    dtype_detect_kernel<<<1, 64, 0, stream>>>(tw1, 128, dflag);

    // ---- prepped-weight region ----
    bf16* WP = (bf16*)(wsb + 256);
    long off = 0;
    WTab tab; tab.n = 0;
    auto alloc = [&](const void* w, int T, int Cout, int Cin) {
        long o = off;
        long tot = wp_elems(T, Cout, Cin);
        tab.e[tab.n++] = WEnt{w, o, tot, Cout, Cin};
        off += tot;
        return o;
    };
    const long o_m1  = alloc(m1_w, 1, 256, 256);
    const long o_m2  = alloc(m2_w, 1, 256, 256);
    const long o_u1a = alloc(u1a_w, 1, 128, 256);
    const long o_u1b = alloc(u1b_w, 1, 128, 128);
    const long o_u2a = alloc(u2a_w, 1, 64, 128);
    const long o_u2b = alloc(u2b_w, 1, 64, 64);
    const long o_mf  = alloc(mf_w, 1, 8, 64);
    const long o_pre = alloc(pre_w, 1, 64, 64);
    const long o_tw0 = alloc(tw0, 8, 96, 64);
    const long o_tw1 = alloc(tw1, 8, 96, 96);
    const long o_tw2 = alloc(tw2, 8, 96, 96);
    const long o_tw3 = alloc(tw3, 8, 64, 96);
    const long o_post = alloc(post_w, 1, 64, 64);
    const long o_up1 = alloc(up1_w, 1, 64, 64);
    const long o_up2 = alloc(up2_w, 1, 64, 64);
    const long o_hr  = alloc(hr_w, 1, 64, 64);
    const long o_fin = alloc(fin_w, 1, 3, 64);
    const long wp_total = off;
    const size_t wp_bytes = (size_t)((wp_total * 2 + 255) & ~255L);

    wprep_all_kernel<<<1024, 256, 0, stream>>>(tab, dflag, WP);

    const long pt_tw0 = wp_elems(1, 96, 64), pt_tw1 = wp_elems(1, 96, 96);
    const long pt_tw3 = wp_elems(1, 64, 96);

    // ---- schedule: batch chunk bc, branch merge tcap, tail strip S ----
    int bc = 1, tcap = 1, S = 16, tc = 1;
    bool found = false;
    for (int c = 16; c >= 1 && !found; c >>= 1) {
        const size_t fixed = 256u + wp_bytes + (size_t)c * 1703936u;
        if (ws_size < fixed) continue;
        const size_t avail = ws_size - fixed;
        const size_t p1 = (size_t)c * 2228224u;                   // phase1
        auto p2 = [&](int t) -> size_t {
            if (t == 1) return (size_t)c * 2621440u;              // no xf
            return (size_t)c * 2u * (524288u + (size_t)t * 1048576u);
        };
        size_t need = p1;
        if (p2(1) > need) need = p2(1);
        if (need < 6291456u) need = 6291456u;
        if (avail < need) continue;
        bc = c; found = true;
        for (int t = 8; t >= 1; t >>= 1)
            if (p2(t) <= avail && p1 <= avail) { tcap = t; break; }
        if (avail >= 18874368u) {
            S = 256; tc = (int)(avail / 18874368u); if (tc > c) tc = c;
        } else if (avail >= 9437184u) S = 64;
        else if (avail >= 7340032u)  S = 32;
        else S = 16;
    }

    char* dyn = wsb + 256 + wp_bytes;
    float* M    = (float*)dyn;                                   // bc*32768 f32
    float* ACC  = (float*)(dyn + (size_t)bc * 131072u);          // bc*262144 f32
    bf16*  OUT2 = (bf16*)(dyn + (size_t)bc * 1179648u);          // bc*262144 bf16
    bf16*  A    = (bf16*)(dyn + (size_t)bc * 1703936u);          // arena

    for (int b0 = 0; b0 < 16; b0 += bc) {
        float* outp = (float*)d_out + (size_t)b0 * 3 * 65536;

        // ---- phase 1: multiplexer ----
        bf16* SP8 = A;
        bf16* f1 = A + (size_t)bc * 65536;
        bf16* f2 = A + (size_t)bc * 131072;
        bf16* g1 = A + (size_t)bc * 196608;
        bf16* g2 = A + (size_t)bc * 327680;
        bf16* h1 = A + (size_t)bc * 458752;
        bf16* h2 = A + (size_t)bc * 720896;

        {
            const long nn = (long)bc * 65536;
            to_nhwc8_kernel<<<1024, 256, 0, stream>>>(sp_all, dflag, SP8, b0, 256, 256, nn);
        }
        conv2(stream, SP8, WP + o_m1, m1_b, f1, 0, 0, bc, 256, 256, 16, 16, 0);
        gn_silu_kernel<<<bc * 8, 256, 0, stream>>>(f1, m1_g, m1_be, dflag, 256, 32, 256);
        conv2(stream, f1, WP + o_m2, nullptr, f2, 0, 0, bc, 256, 256, 16, 16, 0);
        gn_silu_kernel<<<bc * 8, 256, 0, stream>>>(f2, m2_g, m2_be, dflag, 256, 32, 256);
        conv2(stream, f2, WP + o_u1a, nullptr, g1, 0, 0, bc, 256, 128, 32, 32, 1);
        conv2(stream, g1, WP + o_u1b, nullptr, g2, 0, 0, bc, 128, 128, 32, 32, 0);
        gn_silu_kernel<<<bc * 8, 256, 0, stream>>>(g2, u1b_g, u1b_be, dflag, 128, 16, 1024);
        conv2(stream, g2, WP + o_u2a, nullptr, h1, 0, 0, bc, 128, 64, 64, 64, 1);
        conv2(stream, h1, WP + o_u2b, nullptr, h2, 0, 0, bc, 64, 64, 64, 64, 0);
        gn_silu_kernel<<<bc * 8, 256, 0, stream>>>(h2, u2b_g, u2b_be, dflag, 64, 8, 4096);
        conv2(stream, h2, WP + o_mf, nullptr, M, 3, 0, bc, 64, 8, 64, 64, 0);
        softmax_t_kernel<<<(bc * 4096 + 255) / 256, 256, 0, stream>>>(
            M, bc * 4096, 4096, 1.0f / 20.0f);

        // ---- phase 2: stem + branches ----
        bf16* x0   = A;
        bf16* xsp  = A + (size_t)bc * 262144;
        bf16* ping = A + (size_t)bc * 524288;
        bf16* pong = ping + (size_t)tcap * bc * 393216;
        bf16* xf   = pong + (size_t)tcap * bc * 393216;

        conv_init_kernel<<<bc * 16, 256, 0, stream>>>(x_all, init_w, init_b, x0,
                                                      dflag, b0, bc);
        {
            const long nn = (long)bc * 262144;
            addnoise_kernel<<<1024, 256, 0, stream>>>(x0, nz_all, nscale, dflag,
                                                      ping, b0, nn);
        }
        conv2(stream, ping, WP + o_pre, nullptr, xsp, 0, 0, bc, 64, 64, 64, 64, 0);

        const long accn = (long)bc * 262144;
        if (tcap > 1) {
            const int Beff = tcap * bc;
            for (int tg = 0; tg < 8; tg += tcap) {
                conv2(stream, xsp, WP + o_tw0 + (long)tg * pt_tw0, nullptr, ping, 0, 1,
                      Beff, 64, 96, 64, 64, 0, nullptr, nullptr, nullptr, nullptr, 0,
                      bc, pt_tw0, bc);
                conv2(stream, ping, WP + o_tw1 + (long)tg * pt_tw1, nullptr, pong, 0, 1,
                      Beff, 96, 96, 64, 64, 0, nullptr, nullptr, nullptr, nullptr, 0,
                      bc, pt_tw1, 0);
                conv2(stream, pong, WP + o_tw2 + (long)tg * pt_tw1, nullptr, ping, 0, 1,
                      Beff, 96, 96, 64, 64, 0, nullptr, nullptr, nullptr, nullptr, 0,
                      bc, pt_tw1, 0);
                conv2(stream, ping, WP + o_tw3 + (long)tg * pt_tw3, nullptr, xf, 0, 0,
                      Beff, 96, 64, 64, 64, 0, nullptr, nullptr, nullptr, nullptr, 0,
                      bc, pt_tw3, 0);
                acc_att_kernel<<<2048, 256, 0, stream>>>(xf, M, tscale, tbias, dflag,
                                                         ACC, bc, tcap, tg,
                                                         tg == 0 ? 1 : 0, accn);
            }
        } else {
            zero_kernel<<<(int)((accn + 255) / 256), 256, 0, stream>>>(ACC, accn);
            for (int t = 0; t < 8; ++t) {
                conv2(stream, xsp,  WP + o_tw0 + (long)t * pt_tw0, nullptr, ping, 0, 1,
                      bc, 64, 96, 64, 64, 0);
                conv2(stream, ping, WP + o_tw1 + (long)t * pt_tw1, nullptr, pong, 0, 1,
                      bc, 96, 96, 64, 64, 0);
                conv2(stream, pong, WP + o_tw2 + (long)t * pt_tw1, nullptr, ping, 0, 1,
                      bc, 96, 96, 64, 64, 0);
                conv2(stream, ping, WP + o_tw3 + (long)t * pt_tw3, nullptr, ACC, 1, 0,
                      bc, 96, 64, 64, 64, 0, nullptr, M, tscale, tbias, t);
            }
        }

        bf16* outc = xsp;
        combine_kernel<<<(int)((accn + 255) / 256), 256, 0, stream>>>(
            x0, ACC, sscale, dflag, outc, accn);

        conv2(stream, outc, WP + o_post, post_b, OUT2, 2, 0, bc, 64, 64, 64, 64, 0,
              outc, nullptr, pscale, nullptr, 0);

        // ---- phase 3: tail ----
        if (S == 256) {
            bf16* a1 = A;
            bf16* a2 = A + (size_t)tc * 1048576;
            bf16* a3 = A + (size_t)tc * 5242880;
            for (int s0 = 0; s0 < bc; s0 += tc) {
                const int cur = (tc < bc - s0) ? tc : (bc - s0);
                const bf16* src_c = OUT2 + (size_t)s0 * 262144;
                float* out_c = outp + (size_t)s0 * 3 * 65536;
                conv2(stream, src_c, WP + o_up1, up1_b, a1, 0, 1, cur, 64, 64, 128, 128, 1);
                conv2(stream, a1,   WP + o_up2, up2_b, a2, 0, 1, cur, 64, 64, 256, 256, 1);
                conv2(stream, a2,   WP + o_hr,  hr_b,  a3, 0, 1, cur, 64, 64, 256, 256, 0);
                conv2(stream, a3,   WP + o_fin, fin_b, out_c, 3, 0, cur, 64, 3, 256, 256, 0);
            }
        } else {
            bf16* a1  = A;
            bf16* a2s = A + 1048576;
            bf16* a3s = a2s + (size_t)(S + 64) * 16384;
            for (int i = 0; i < bc; ++i) {
                const bf16* src_i = OUT2 + (size_t)i * 262144;
                float* out_i = outp + (size_t)i * 3 * 65536;
                conv2(stream, src_i, WP + o_up1, up1_b, a1, 0, 1, 1, 64, 64, 128, 128, 1);
                for (int r0 = 0; r0 < 256; r0 += S) {
                    const int r1 = r0 + S;
                    const int w2a = (r0 - 32 > 0) ? r0 - 32 : 0;
                    const int w2b = (r1 + 32 < 256) ? r1 + 32 : 256;
                    const int w3a = (r0 - 16 > 0) ? r0 - 16 : 0;
                    const int w3b = (r1 + 16 < 256) ? r1 + 16 : 256;
                    conv2w(stream, a1, WP + o_up2, up2_b, a2s, 0, 1,
                           1, 64, 64, 256, 256, 1,
                           0, 128, w2a, w2b - w2a, w2a, w2b - w2a);
                    conv2w(stream, a2s, WP + o_hr, hr_b, a3s, 0, 1,
                           1, 64, 64, 256, 256, 0,
                           w2a, w2b - w2a, w3a, w3b - w3a, w3a, w3b - w3a);
                    conv2w(stream, a3s, WP + o_fin, fin_b, out_i, 3, 0,
                           1, 64, 3, 256, 256, 0,
                           w3a, w3b - w3a, 0, 256, r0, S);
                }
            }
        }
    }
}

// Round 11
// 1228.542 us; speedup vs baseline: 1.0884x; 1.0884x over previous
//
#include <hip/hip_runtime.h>
#include <hip/hip_bf16.h>
#include <math.h>

typedef __hip_bfloat16 bf16;

#define LRELU(v) ((v) >= 0.f ? (v) : 0.2f * (v))

__device__ __forceinline__ float b2f(bf16 v) { return __bfloat162float(v); }
__device__ __forceinline__ bf16 f2b(float v) { return __float2bfloat16(v); }

__device__ __forceinline__ float eload(const void* p, long i, int isf32)
{
    return isf32 ? ((const float*)p)[i] : b2f(((const bf16*)p)[i]);
}

union BfPack { short4 s; bf16 h[4]; };
typedef __attribute__((ext_vector_type(8))) short bfrag_t;   // 8 bf16
typedef __attribute__((ext_vector_type(4))) float ffrag_t;   // 4 f32 acc
union PackU { bfrag_t v; bf16 b[8]; };

// async global->LDS, 16B per lane; LDS dest = wave-uniform base + lane*16
__device__ __forceinline__ void gload_lds16(const bf16* g, bf16* l)
{
    __builtin_amdgcn_global_load_lds(
        (const __attribute__((address_space(1))) void*)g,
        (__attribute__((address_space(3))) void*)l,
        16, 0, 0);
}

// ---------------------------------------------------------------------------
__global__ void dtype_detect_kernel(const void* probe, int n, int* flag)
{
    if (threadIdx.x == 0 && blockIdx.x == 0) {
        const bf16* e = (const bf16*)probe;
        int f32 = 0;
        for (int i = 0; i < n; ++i) {
            const float v = b2f(e[i]);
            if (!(v > -1.0f && v < 1.0f)) f32 = 1;
        }
        *flag = f32;
    }
}

// planar external [b0+b][C][HW] -> NHWC8 bf16 [b][C/8][HW][8]
__global__ void __launch_bounds__(256)
to_nhwc8_kernel(const void* __restrict__ src, const int* __restrict__ dflag,
                bf16* __restrict__ out, int b_off, int C, int HW, long n)
{
    const int ef = dflag[0];
    const int CG = C >> 3;
    for (long i = (long)blockIdx.x * 256 + threadIdx.x; i < n;
         i += (long)gridDim.x * 256) {
        const int c8 = (int)(i & 7);
        long r = i >> 3;
        const int p = (int)(r % HW); r /= HW;
        const int cg = (int)(r % CG);
        const int b = (int)(r / CG);
        out[i] = f2b(eload(src, ((long)(b_off + b) * C + cg * 8 + c8) * HW + p, ef));
    }
}

// xs(NHWC8) = x0(NHWC8) + ns * noise(planar ext), C=64, HW=4096
__global__ void __launch_bounds__(256)
addnoise_kernel(const bf16* __restrict__ x0, const void* __restrict__ noise,
                const void* __restrict__ ns_ptr, const int* __restrict__ dflag,
                bf16* __restrict__ out, int b_off, long n)
{
    const int ef = dflag[0];
    const float ns = eload(ns_ptr, 0, ef);
    for (long i = (long)blockIdx.x * 256 + threadIdx.x; i < n;
         i += (long)gridDim.x * 256) {
        const int c8 = (int)(i & 7);
        long r = i >> 3;
        const int p = (int)(r % 4096); r /= 4096;
        const int cg = (int)(r % 8);
        const int b = (int)(r / 8);
        out[i] = f2b(b2f(x0[i]) +
                     ns * eload(noise, ((long)(b_off + b) * 64 + cg * 8 + c8) * 4096 + p, ef));
    }
}

// ---------------------------------------------------------------------------
// single-launch weight prep: external [t][co][ci][3][3] ->
//   wp[t][cog][cc][tap][...] bf16, A-fragment-ready, zero-pad co.
// Intra-tap layout is LANE-LINEAR for conflict-free ds_read_b128:
//   element A[co][ci] at position co*8 + (ci>>3)*128 + (ci&7)
// so lane l=16q+n (reading co=n, ci=q*8..q*8+7 at offset q*128+n*8) maps to
// slot l -> a wave reads 1024 contiguous bytes (banking floor, 0 conflicts).
// ---------------------------------------------------------------------------
struct WEnt { const void* src; long dst_off; long total; int Cout; int Cin; };
struct WTab { WEnt e[17]; int n; };

__global__ void __launch_bounds__(256)
wprep_all_kernel(WTab tab, const int* __restrict__ dflag, bf16* __restrict__ out)
{
    const int ef = dflag[0];
    for (int k = 0; k < tab.n; ++k) {
        const WEnt E = tab.e[k];
        const int cogs = (E.Cout + 15) >> 4, ccs = E.Cin >> 5;
        const long src_t = (long)E.Cout * E.Cin * 9;
        for (long i = (long)blockIdx.x * 256 + threadIdx.x; i < E.total;
             i += (long)gridDim.x * 256) {
            const int e = (int)(i & 511);
            long r = i >> 9;
            const int tap = (int)(r % 9); r /= 9;
            const int cc = (int)(r % ccs); r /= ccs;
            const int cog = (int)(r % cogs);
            const int t = (int)(r / cogs);
            const int nn = (e >> 3) & 15;            // co (lane-linear layout)
            const int kk = (e >> 7) * 8 + (e & 7);   // ci
            const int co = cog * 16 + nn, ci = cc * 32 + kk;
            float v = 0.f;
            if (co < E.Cout)
                v = eload(E.src, (long)t * src_t + ((long)co * E.Cin + ci) * 9 + tap, ef);
            out[E.dst_off + i] = f2b(v);
        }
    }
}

// ---------------------------------------------------------------------------
// MFMA implicit-GEMM 3x3 conv, NHWC8 src, prepped weights.
// Tile 16x16 px; block handles CPB consecutive cogs (CPB | cogs guaranteed).
// CPB<=3 (48 AGPR) + __launch_bounds__(256,4).
// XCD-aware bijective block swizzle (T1/m204): bid = x*q + min(x,r) + (d>>3).
// Weight fragments staged in LDS (sW) per chunk via global_load_lds width=16
// (m193 fast path: coalesced source, LDS dst = wave-uniform base + lane*16);
// lane-linear fragment layout (see wprep) -> conflict-free sW ds_reads.
// Descriptor arrays sized per-CPB (constexpr KW) so CPB=1/2 instantiations
// don't carry CPB=3's register pressure (R10 total regression suspect).
// Src staging: reg path (scattered addrs), fused load->ds_write per granule,
// hoisted descriptors. OOB halo zeroed once in prologue. Compute phase is
// pure LDS+MFMA (no VMEM) so in-flight weight loads drain at the barrier.
// img_per_t>0: per-image-group weights (merged branches), weight idx = b/img_per_t.
// src_bmod>0: src image index = b % src_bmod (shared-input merged conv).
// dst_kind: 0=NHWC8 bf16 (+act), 1=NHWC8 f32 += (v*es[e]+eb[e])*att,
//           2=NHWC8 bf16 resid + lrelu(v)*es[0], 3=planar f32 (+act).
// ---------------------------------------------------------------------------
template <int CPB>
__global__ void __launch_bounds__(256, 4)
conv_mfma(const bf16* __restrict__ src,
          const bf16* __restrict__ wp,
          const void* __restrict__ bias,
          void* __restrict__ dst, int dst_kind, int act,
          const bf16* __restrict__ resid,
          const float* __restrict__ att,
          const void* __restrict__ es_ptr, const void* __restrict__ eb_ptr,
          int e_idx,
          const int* __restrict__ dflag,
          int B, int Cin, int Cout, int H, int W, int up,
          int cog_blocks,
          int src_row0, int src_rows, int dst_row0, int dst_rows_buf,
          int dst_y0, int dst_rows,
          int img_per_t, long wstride, int src_bmod)
{
    __shared__ __align__(16) bf16 sI[324 * 32];      // 20,736 B
    __shared__ __align__(16) bf16 sW[CPB * 4608];    // 9,216 B per cog

    constexpr int KW = (CPB * 576 + 255) / 256;      // weight granule iters

    const int ef = dflag[0];
    const int ccs  = Cin >> 5;
    const int CGi = Cin >> 3;
    const int CGo = Cout >> 3;
    const int tilesX = W >> 4;
    const int tilesY = dst_rows >> 4;
    const int inW = up ? (W >> 1) : W;

    // ---- XCD-aware bijective remap (m204, simplified chunk-start form) ----
    int bid;
    {
        const unsigned d = blockIdx.x, nwg = gridDim.x;
        const unsigned qq = nwg >> 3, rr = nwg & 7;
        const unsigned x = d & 7;
        bid = (int)(x * qq + (x < rr ? x : rr) + (d >> 3));
    }
    const int cogb = bid % cog_blocks; bid /= cog_blocks;
    const int tx = bid % tilesX; bid /= tilesX;
    const int ty = bid % tilesY;
    const int b  = bid / tilesY;
    const int cog0 = cogb * CPB;
    const int sbi = src_bmod ? (b % src_bmod) : b;
    const bf16* wpb = wp + (img_per_t ? (long)(b / img_per_t) * wstride : 0);

    const int tid = threadIdx.x;
    const int wave = tid >> 6, lane = tid & 63;
    const int n = lane & 15, q = lane >> 4;
    const int yb = dst_y0 + ty * 16, xb = tx * 16;
    const int r0w = wave * 4;

    int cb[3];
#pragma unroll
    for (int d = 0; d < 3; ++d) {
        const int tc = n + d;
        cb[d] = tc * 32 + ((q ^ ((tc >> 1) & 3)) << 3);
    }

    // ---- hoisted src staging descriptors (constant across cc chunks) ----
    unsigned gofs[6];            // element offset at cc=0 (valid iff vmask bit)
    int      lofs[6];            // LDS element offset (swizzled)
    unsigned vmask = 0;
    const unsigned ccstep = (unsigned)((4 * src_rows * inW) << 3);
#pragma unroll
    for (int k = 0; k < 6; ++k) {
        gofs[k] = 0; lofs[k] = 0;
        const int i = tid + k * 256;
        if (i < 1296) {
            const int pc = i % 324;
            const int cig = i / 324;
            const int trow = pc / 18, tcol = pc - trow * 18;
            lofs[k] = pc * 32 + ((cig ^ ((tcol >> 1) & 3)) << 3);
            const int iy = yb + trow - 1, ix = xb + tcol - 1;
            if (iy >= 0 && iy < H && ix >= 0 && ix < W) {
                const int sy = up ? (iy >> 1) : iy;
                const int sx = up ? (ix >> 1) : ix;
                gofs[k] = (unsigned)(((((long)sbi * CGi + cig) * src_rows
                                      + (sy - src_row0)) * inW + sx) << 3);
                vmask |= 1u << k;
            }
        }
    }

    // ---- hoisted weight staging descriptors (divisions once, not per cc) ----
    const long wc_cstride = (long)ccs * 4608;   // per-cog stride in wp
    unsigned wofs[KW];
#pragma unroll
    for (int k = 0; k < KW; ++k) {
        wofs[k] = 0;
        const int g = tid + k * 256;
        if (g < CPB * 576) {
            const int c = g / 576;
            wofs[k] = (unsigned)((long)g * 8 + (long)c * (wc_cstride - 4608));
        }
    }

    // ---- one-time zero of OOB halo slots (never rewritten) ----
    {
        PackU z;
#pragma unroll
        for (int j = 0; j < 8; ++j) z.b[j] = f2b(0.0f);
#pragma unroll
        for (int k = 0; k < 6; ++k)
            if ((tid + k * 256 < 1296) && !(vmask & (1u << k)))
                *(bfrag_t*)&sI[lofs[k]] = z.v;
    }

    ffrag_t acc[CPB][4];
#pragma unroll
    for (int c = 0; c < CPB; ++c)
#pragma unroll
        for (int g = 0; g < 4; ++g) acc[c][g] = (ffrag_t){0.f, 0.f, 0.f, 0.f};

    const bf16* wsrc = wpb + (long)cog0 * ccs * 4608;

    for (int cc = 0; cc < ccs; ++cc) {
        // ---- stage weight fragments: async direct-to-LDS (coalesced src) ----
#pragma unroll
        for (int k = 0; k < KW; ++k) {
            const int g = tid + k * 256;
            if (g < CPB * 576)
                gload_lds16(&wsrc[wofs[k]], &sW[g * 8]);
        }
        wsrc += 4608;
        // ---- stage src chunk cc: fused load->write per granule ----
#pragma unroll
        for (int k = 0; k < 6; ++k) {
            if (vmask & (1u << k)) {
                const bfrag_t v = *(const bfrag_t*)&src[gofs[k]];
                *(bfrag_t*)&sI[lofs[k]] = v;
                gofs[k] += ccstep;
            }
        }
        __syncthreads();

        // ---- compute: pure LDS + MFMA, conflict-free sW reads ----
#pragma unroll
        for (int dx = 0; dx < 3; ++dx) {
            bfrag_t bcol[6];
#pragma unroll
            for (int rr = 0; rr < 6; ++rr)
                bcol[rr] = *(const bfrag_t*)&sI[(r0w + rr) * 18 * 32 + cb[dx]];
#pragma unroll
            for (int c = 0; c < CPB; ++c) {
                const bf16* wbase = &sW[c * 4608 + q * 128 + n * 8];
#pragma unroll
                for (int dy = 0; dy < 3; ++dy) {
                    const bfrag_t a = *(const bfrag_t*)&wbase[(dy * 3 + dx) * 512];
#pragma unroll
                    for (int g = 0; g < 4; ++g)
                        acc[c][g] = __builtin_amdgcn_mfma_f32_16x16x32_bf16(
                            a, bcol[g + dy], acc[c][g], 0, 0, 0);
                }
            }
        }
        __syncthreads();
    }

    // ---- epilogue ----
    const float es  = es_ptr ? eload(es_ptr, e_idx, ef) : 1.0f;
    const float ebv = eb_ptr ? eload(eb_ptr, e_idx, ef) : 0.0f;
    const int x = xb + n;
#pragma unroll
    for (int c = 0; c < CPB; ++c) {
        const int cog = cog0 + c;
        if (dst_kind == 3) {
#pragma unroll
            for (int g = 0; g < 4; ++g) {
                const int y = yb + r0w + g, yr = y - dst_row0;
#pragma unroll
                for (int reg = 0; reg < 4; ++reg) {
                    const int co = cog * 16 + q * 4 + reg;
                    if (co < Cout) {
                        float v = acc[c][g][reg];
                        if (bias) v += eload(bias, co, ef);
                        if (act) v = LRELU(v);
                        ((float*)dst)[(((long)b * Cout + co) * dst_rows_buf + yr) * W + x] = v;
                    }
                }
            }
            continue;
        }
        const int cg = cog * 2 + (q >> 1);
        const int c8 = (q & 1) * 4;
        float bv[4];
#pragma unroll
        for (int reg = 0; reg < 4; ++reg)
            bv[reg] = bias ? eload(bias, cog * 16 + q * 4 + reg, ef) : 0.0f;
#pragma unroll
        for (int g = 0; g < 4; ++g) {
            const int y = yb + r0w + g, yr = y - dst_row0;
            const long base = ((((long)b * CGo + cg) * dst_rows_buf + yr) * W + x) * 8 + c8;
            if (dst_kind == 0) {
                BfPack o;
#pragma unroll
                for (int reg = 0; reg < 4; ++reg) {
                    float v = acc[c][g][reg] + bv[reg];
                    if (act) v = LRELU(v);
                    o.h[reg] = f2b(v);
                }
                *(short4*)&((bf16*)dst)[base] = o.s;
            } else if (dst_kind == 1) {
                const float attv = att[(((long)b * 8 + e_idx) * H + y) * W + x];
                float* dp = (float*)dst + base;
                float4 dv = *(float4*)dp;
                dv.x += ((acc[c][g][0] + bv[0]) * es + ebv) * attv;
                dv.y += ((acc[c][g][1] + bv[1]) * es + ebv) * attv;
                dv.z += ((acc[c][g][2] + bv[2]) * es + ebv) * attv;
                dv.w += ((acc[c][g][3] + bv[3]) * es + ebv) * attv;
                *(float4*)dp = dv;
            } else {
                BfPack rv; rv.s = *(const short4*)&resid[base];
                BfPack o;
#pragma unroll
                for (int reg = 0; reg < 4; ++reg) {
                    const float v = acc[c][g][reg] + bv[reg];
                    o.h[reg] = f2b(b2f(rv.h[reg]) + LRELU(v) * es);
                }
                *(short4*)&((bf16*)dst)[base] = o.s;
            }
        }
    }
}

// ---------------------------------------------------------------------------
// ACC (+)= sum_t (xf[t] * tscale[t] + tbias[t]) * att[b,t,:]
// xf: NHWC8 bf16, images [ti*bc + b]; ACC: NHWC8 f32 over bc images.
// ---------------------------------------------------------------------------
__global__ void __launch_bounds__(256)
acc_att_kernel(const bf16* __restrict__ xf, const float* __restrict__ att,
               const void* __restrict__ ts, const void* __restrict__ tb,
               const int* __restrict__ dflag, float* __restrict__ ACC,
               int bc, int tcap, int tgrp, int init, long n)
{
    const int ef = dflag[0];
    for (long i = (long)blockIdx.x * 256 + threadIdx.x; i < n;
         i += (long)gridDim.x * 256) {
        long r = i >> 3;
        const int p = (int)(r % 4096); r /= 4096;
        r /= 8;                         // skip cg
        const int b = (int)r;
        float s = init ? 0.f : ACC[i];
        for (int ti = 0; ti < tcap; ++ti) {
            const int t = tgrp + ti;
            const float a = att[((long)b * 8 + t) * 4096 + p];
            const float v = b2f(xf[(long)ti * bc * 262144 + i]);
            s += (v * eload(ts, t, ef) + eload(tb, t, ef)) * a;
        }
        ACC[i] = s;
    }
}

// ---------------------------------------------------------------------------
// init conv: planar ext x [b0+b][3][64][64] -> NHWC8 x0, Cout=64
// ---------------------------------------------------------------------------
__global__ void __launch_bounds__(256)
conv_init_kernel(const void* __restrict__ src, const void* __restrict__ wgt,
                 const void* __restrict__ bias, bf16* __restrict__ dst,
                 const int* __restrict__ dflag, int b_off, int B)
{
    __shared__ float slds[3 * 34 * 36];
    __shared__ float wlds[3 * 16 * 12];
    const int ef = dflag[0];

    int bid = blockIdx.x;
    const int coI = bid & 3; bid >>= 2;
    const int tx = bid & 1; bid >>= 1;
    const int ty = bid & 1; bid >>= 1;
    const int b = bid;
    const int co0 = coI * 16;
    const int tid = threadIdx.x;
    const int wave = tid >> 6, lane = tid & 63;
    const int ty4 = lane >> 3, tx4 = lane & 7;
    const int yb = ty * 32, xb = tx * 32;

    for (int i = tid; i < 34 * 34 * 3; i += 256) {
        const int c = i / 1156, p = i % 1156;
        const int row = p / 34, col = p % 34;
        const int iy = yb + row - 1, ix = xb + col - 1;
        float v = 0.f;
        if (iy >= 0 && iy < 64 && ix >= 0 && ix < 64)
            v = eload(src, ((long)(b_off + b) * 3 + c) * 4096 + iy * 64 + ix, ef);
        slds[(c * 34 + row) * 36 + col] = v;
    }
    for (int i = tid; i < 3 * 144; i += 256) {
        const int ci = i / 144, r = i % 144;
        const int co = r / 9, k = r % 9;
        wlds[(ci * 16 + co) * 12 + k] = eload(wgt, ((long)(co0 + co) * 3 + ci) * 9 + k, ef);
    }
    __syncthreads();

    float acc[4][16];
#pragma unroll
    for (int i = 0; i < 4; ++i)
#pragma unroll
        for (int j = 0; j < 16; ++j) acc[i][j] = 0.f;

    for (int ci = 0; ci < 3; ++ci) {
        float in[6][6];
        const float* sp = &slds[(ci * 34 + ty4 * 4) * 36 + tx4 * 4];
#pragma unroll
        for (int r = 0; r < 6; ++r) {
            const float4 v4 = *(const float4*)(sp + r * 36);
            const float2 v2 = *(const float2*)(sp + r * 36 + 4);
            in[r][0] = v4.x; in[r][1] = v4.y; in[r][2] = v4.z; in[r][3] = v4.w;
            in[r][4] = v2.x; in[r][5] = v2.y;
        }
#pragma unroll
        for (int cc = 0; cc < 4; ++cc) {
            const float* wp = &wlds[(ci * 16 + wave * 4 + cc) * 12];
            const float4 wa = *(const float4*)wp;
            const float4 wb = *(const float4*)(wp + 4);
            const float w8 = wp[8];
#pragma unroll
            for (int r = 0; r < 4; ++r)
#pragma unroll
                for (int c = 0; c < 4; ++c)
                    acc[cc][r * 4 + c] += in[r][c] * wa.x + in[r][c+1] * wa.y + in[r][c+2] * wa.z
                        + in[r+1][c] * wa.w + in[r+1][c+1] * wb.x + in[r+1][c+2] * wb.y
                        + in[r+2][c] * wb.z + in[r+2][c+1] * wb.w + in[r+2][c+2] * w8;
        }
    }

    const int cg = coI * 2 + (wave >> 1);
    const int c8 = (wave & 1) * 4;
    float bv[4];
#pragma unroll
    for (int cc = 0; cc < 4; ++cc)
        bv[cc] = bias ? eload(bias, co0 + wave * 4 + cc, ef) : 0.0f;
#pragma unroll
    for (int r = 0; r < 4; ++r) {
        const int y = yb + ty4 * 4 + r;
#pragma unroll
        for (int c = 0; c < 4; ++c) {
            const int x = xb + tx4 * 4 + c;
            BfPack o;
#pragma unroll
            for (int cc = 0; cc < 4; ++cc)
                o.h[cc] = f2b(acc[cc][r * 4 + c] + bv[cc]);
            *(short4*)&dst[((((long)b * 8 + cg) * 64 + y) * 64 + x) * 8 + c8] = o.s;
        }
    }
}

// ---------------------------------------------------------------------------
__global__ void __launch_bounds__(256)
gn_silu_kernel(bf16* __restrict__ d, const void* __restrict__ g,
               const void* __restrict__ be, const int* __restrict__ dflag,
               int C, int gsize, int HW)
{
    const int ef = dflag[0];
    const int groups = C / gsize;
    const int blk = blockIdx.x;
    const int b  = blk / groups;
    const int gr = blk % groups;
    const long base = ((long)b * (C >> 3) + (long)gr * (gsize >> 3)) * HW * 8;
    const int N = gsize * HW;

    float s = 0.0f, ss = 0.0f;
    for (int i = threadIdx.x; i < N; i += 256) {
        const float v = b2f(d[base + i]);
        s += v; ss += v * v;
    }
    __shared__ float rs[256], rss[256];
    rs[threadIdx.x] = s; rss[threadIdx.x] = ss;
    __syncthreads();
    for (int o = 128; o > 0; o >>= 1) {
        if (threadIdx.x < o) {
            rs[threadIdx.x]  += rs[threadIdx.x + o];
            rss[threadIdx.x] += rss[threadIdx.x + o];
        }
        __syncthreads();
    }
    __shared__ float mean_s, inv_s;
    if (threadIdx.x == 0) {
        const float mean = rs[0] / (float)N;
        const float var  = rss[0] / (float)N - mean * mean;
        mean_s = mean; inv_s = rsqrtf(var + 1e-5f);
    }
    __syncthreads();
    const float mean = mean_s, inv = inv_s;
    for (int i = threadIdx.x; i < N; i += 256) {
        const int c = gr * gsize + (i / (HW * 8)) * 8 + (i & 7);
        const float v  = b2f(d[base + i]);
        const float xn = (v - mean) * inv * eload(g, c, ef) + eload(be, c, ef);
        d[base + i] = f2b(xn / (1.0f + expf(-xn)));
    }
}

__global__ void __launch_bounds__(256)
softmax_t_kernel(float* __restrict__ m, int BHW, int HW, float invtemp)
{
    const int i = blockIdx.x * 256 + threadIdx.x;
    if (i >= BHW) return;
    const int b = i / HW;
    const int p = i % HW;
    const long base = (long)b * 8 * HW + p;
    float v[8];
    float mx = -1e30f;
#pragma unroll
    for (int t = 0; t < 8; ++t) {
        v[t] = m[base + (long)t * HW] * invtemp;
        mx = fmaxf(mx, v[t]);
    }
    float s = 0.0f;
#pragma unroll
    for (int t = 0; t < 8; ++t) { v[t] = expf(v[t] - mx); s += v[t]; }
    const float r = 1.0f / s;
#pragma unroll
    for (int t = 0; t < 8; ++t) m[base + (long)t * HW] = v[t] * r;
}

__global__ void __launch_bounds__(256)
combine_kernel(const bf16* __restrict__ x0, const float* __restrict__ acc,
               const void* __restrict__ ss, const int* __restrict__ dflag,
               bf16* __restrict__ out, long n)
{
    const long i = (long)blockIdx.x * 256 + threadIdx.x;
    if (i < n) out[i] = f2b(b2f(x0[i]) + acc[i] * eload(ss, 0, dflag[0]));
}

__global__ void __launch_bounds__(256)
zero_kernel(float* __restrict__ p, long n)
{
    const long i = (long)blockIdx.x * 256 + threadIdx.x;
    if (i < n) p[i] = 0.0f;
}

// ---------------------------------------------------------------------------
static const int* g_dflag;

static void conv2w(hipStream_t st, const bf16* src, const bf16* wp,
                   const void* bias, void* dst, int dst_kind, int act,
                   int B, int Cin, int Cout, int H, int W, int up,
                   int src_row0, int src_rows, int dst_row0, int dst_rows_buf,
                   int dst_y0, int dst_rows,
                   const bf16* resid = nullptr, const float* att = nullptr,
                   const void* es = nullptr, const void* eb = nullptr, int eidx = 0,
                   int img_per_t = 0, long wstride = 0, int src_bmod = 0)
{
    const int cogs = (Cout + 15) >> 4;
    const int spatial = B * (dst_rows >> 4) * (W >> 4);
    // CPB: largest divisor of cogs (<=3, 48 AGPR cap) whose block count
    // fills residency (>=1024); else 1.
    static const int cands[3] = {3, 2, 1};
    int cpb = 1;
    for (int k = 0; k < 3; ++k) {
        const int c = cands[k];
        if (cogs % c) continue;
        if ((long)spatial * (cogs / c) >= 1024) { cpb = c; break; }
        if (c == 1) cpb = 1;   // tiny spatial: max blocks, L2 eats restaging
    }
    const int cogb = cogs / cpb;
    const int blocks = spatial * cogb;
#define LAUNCH(CP) conv_mfma<CP><<<blocks, 256, 0, st>>>( \
        src, wp, bias, dst, dst_kind, act, resid, att, es, eb, eidx, g_dflag, \
        B, Cin, Cout, H, W, up, cogb, \
        src_row0, src_rows, dst_row0, dst_rows_buf, dst_y0, dst_rows, \
        img_per_t, wstride, src_bmod)
    switch (cpb) {
        case 3: LAUNCH(3); break;
        case 2: LAUNCH(2); break;
        default: LAUNCH(1); break;
    }
#undef LAUNCH
}

static void conv2(hipStream_t st, const bf16* src, const bf16* wp,
                  const void* bias, void* dst, int dst_kind, int act,
                  int B, int Cin, int Cout, int H, int W, int up,
                  const bf16* resid = nullptr, const float* att = nullptr,
                  const void* es = nullptr, const void* eb = nullptr, int eidx = 0,
                  int img_per_t = 0, long wstride = 0, int src_bmod = 0)
{
    conv2w(st, src, wp, bias, dst, dst_kind, act, B, Cin, Cout, H, W, up,
           0, up ? (H >> 1) : H, 0, H, 0, H, resid, att, es, eb, eidx,
           img_per_t, wstride, src_bmod);
}

static long wp_elems(int T, int Cout, int Cin)
{
    return (long)T * ((Cout + 15) / 16) * (Cin / 32) * 9 * 512;
}

extern "C" void kernel_launch(void* const* d_in, const int* in_sizes, int n_in,
                              void* d_out, int out_size, void* d_ws, size_t ws_size,
                              hipStream_t stream)
{
    const void* x_all   = d_in[0];
    const void* sp_all  = d_in[1];
    const void* nz_all  = d_in[2];
    const void* init_w  = d_in[3];
    const void* init_b  = d_in[4];
    const void* pre_w   = d_in[5];
    const void* tw0     = d_in[6];
    const void* tw1     = d_in[7];
    const void* tw2     = d_in[8];
    const void* tw3     = d_in[9];
    const void* tscale  = d_in[10];
    const void* tbias   = d_in[11];
    const void* nscale  = d_in[12];
    const void* sscale  = d_in[13];
    const void* pscale  = d_in[14];
    const void* post_w  = d_in[15];
    const void* post_b  = d_in[16];
    const void* m1_w    = d_in[17];
    const void* m1_b    = d_in[18];
    const void* m1_g    = d_in[19];
    const void* m1_be   = d_in[20];
    const void* m2_w    = d_in[21];
    const void* m2_g    = d_in[22];
    const void* m2_be   = d_in[23];
    const void* u1a_w   = d_in[24];
    const void* u1b_w   = d_in[25];
    const void* u1b_g   = d_in[26];
    const void* u1b_be  = d_in[27];
    const void* u2a_w   = d_in[28];
    const void* u2b_w   = d_in[29];
    const void* u2b_g   = d_in[30];
    const void* u2b_be  = d_in[31];
    const void* mf_w    = d_in[32];
    const void* up1_w   = d_in[33];
    const void* up1_b   = d_in[34];
    const void* up2_w   = d_in[35];
    const void* up2_b   = d_in[36];
    const void* hr_w    = d_in[37];
    const void* hr_b    = d_in[38];
    const void* fin_w   = d_in[39];
    const void* fin_b   = d_in[40];
    (void)in_sizes; (void)n_in; (void)out_size;

    char* wsb = (char*)d_ws;
    int* dflag = (int*)wsb;
    g_dflag = dflag;
    dtype_detect_kernel<<<1, 64, 0, stream>>>(tw1, 128, dflag);

    // ---- prepped-weight region ----
    bf16* WP = (bf16*)(wsb + 256);
    long off = 0;
    WTab tab; tab.n = 0;
    auto alloc = [&](const void* w, int T, int Cout, int Cin) {
        long o = off;
        long tot = wp_elems(T, Cout, Cin);
        tab.e[tab.n++] = WEnt{w, o, tot, Cout, Cin};
        off += tot;
        return o;
    };
    const long o_m1  = alloc(m1_w, 1, 256, 256);
    const long o_m2  = alloc(m2_w, 1, 256, 256);
    const long o_u1a = alloc(u1a_w, 1, 128, 256);
    const long o_u1b = alloc(u1b_w, 1, 128, 128);
    const long o_u2a = alloc(u2a_w, 1, 64, 128);
    const long o_u2b = alloc(u2b_w, 1, 64, 64);
    const long o_mf  = alloc(mf_w, 1, 8, 64);
    const long o_pre = alloc(pre_w, 1, 64, 64);
    const long o_tw0 = alloc(tw0, 8, 96, 64);
    const long o_tw1 = alloc(tw1, 8, 96, 96);
    const long o_tw2 = alloc(tw2, 8, 96, 96);
    const long o_tw3 = alloc(tw3, 8, 64, 96);
    const long o_post = alloc(post_w, 1, 64, 64);
    const long o_up1 = alloc(up1_w, 1, 64, 64);
    const long o_up2 = alloc(up2_w, 1, 64, 64);
    const long o_hr  = alloc(hr_w, 1, 64, 64);
    const long o_fin = alloc(fin_w, 1, 3, 64);
    const long wp_total = off;
    const size_t wp_bytes = (size_t)((wp_total * 2 + 255) & ~255L);

    wprep_all_kernel<<<1024, 256, 0, stream>>>(tab, dflag, WP);

    const long pt_tw0 = wp_elems(1, 96, 64), pt_tw1 = wp_elems(1, 96, 96);
    const long pt_tw3 = wp_elems(1, 64, 96);

    // ---- schedule: batch chunk bc, branch merge tcap, tail strip S ----
    int bc = 1, tcap = 1, S = 16, tc = 1;
    bool found = false;
    for (int c = 16; c >= 1 && !found; c >>= 1) {
        const size_t fixed = 256u + wp_bytes + (size_t)c * 1703936u;
        if (ws_size < fixed) continue;
        const size_t avail = ws_size - fixed;
        const size_t p1 = (size_t)c * 2228224u;                   // phase1
        auto p2 = [&](int t) -> size_t {
            if (t == 1) return (size_t)c * 2621440u;              // no xf
            return (size_t)c * 2u * (524288u + (size_t)t * 1048576u);
        };
        size_t need = p1;
        if (p2(1) > need) need = p2(1);
        if (need < 6291456u) need = 6291456u;
        if (avail < need) continue;
        bc = c; found = true;
        for (int t = 8; t >= 1; t >>= 1)
            if (p2(t) <= avail && p1 <= avail) { tcap = t; break; }
        if (avail >= 18874368u) {
            S = 256; tc = (int)(avail / 18874368u); if (tc > c) tc = c;
        } else if (avail >= 9437184u) S = 64;
        else if (avail >= 7340032u)  S = 32;
        else S = 16;
    }

    char* dyn = wsb + 256 + wp_bytes;
    float* M    = (float*)dyn;                                   // bc*32768 f32
    float* ACC  = (float*)(dyn + (size_t)bc * 131072u);          // bc*262144 f32
    bf16*  OUT2 = (bf16*)(dyn + (size_t)bc * 1179648u);          // bc*262144 bf16
    bf16*  A    = (bf16*)(dyn + (size_t)bc * 1703936u);          // arena

    for (int b0 = 0; b0 < 16; b0 += bc) {
        float* outp = (float*)d_out + (size_t)b0 * 3 * 65536;

        // ---- phase 1: multiplexer ----
        bf16* SP8 = A;
        bf16* f1 = A + (size_t)bc * 65536;
        bf16* f2 = A + (size_t)bc * 131072;
        bf16* g1 = A + (size_t)bc * 196608;
        bf16* g2 = A + (size_t)bc * 327680;
        bf16* h1 = A + (size_t)bc * 458752;
        bf16* h2 = A + (size_t)bc * 720896;

        {
            const long nn = (long)bc * 65536;
            to_nhwc8_kernel<<<1024, 256, 0, stream>>>(sp_all, dflag, SP8, b0, 256, 256, nn);
        }
        conv2(stream, SP8, WP + o_m1, m1_b, f1, 0, 0, bc, 256, 256, 16, 16, 0);
        gn_silu_kernel<<<bc * 8, 256, 0, stream>>>(f1, m1_g, m1_be, dflag, 256, 32, 256);
        conv2(stream, f1, WP + o_m2, nullptr, f2, 0, 0, bc, 256, 256, 16, 16, 0);
        gn_silu_kernel<<<bc * 8, 256, 0, stream>>>(f2, m2_g, m2_be, dflag, 256, 32, 256);
        conv2(stream, f2, WP + o_u1a, nullptr, g1, 0, 0, bc, 256, 128, 32, 32, 1);
        conv2(stream, g1, WP + o_u1b, nullptr, g2, 0, 0, bc, 128, 128, 32, 32, 0);
        gn_silu_kernel<<<bc * 8, 256, 0, stream>>>(g2, u1b_g, u1b_be, dflag, 128, 16, 1024);
        conv2(stream, g2, WP + o_u2a, nullptr, h1, 0, 0, bc, 128, 64, 64, 64, 1);
        conv2(stream, h1, WP + o_u2b, nullptr, h2, 0, 0, bc, 64, 64, 64, 64, 0);
        gn_silu_kernel<<<bc * 8, 256, 0, stream>>>(h2, u2b_g, u2b_be, dflag, 64, 8, 4096);
        conv2(stream, h2, WP + o_mf, nullptr, M, 3, 0, bc, 64, 8, 64, 64, 0);
        softmax_t_kernel<<<(bc * 4096 + 255) / 256, 256, 0, stream>>>(
            M, bc * 4096, 4096, 1.0f / 20.0f);

        // ---- phase 2: stem + branches ----
        bf16* x0   = A;
        bf16* xsp  = A + (size_t)bc * 262144;
        bf16* ping = A + (size_t)bc * 524288;
        bf16* pong = ping + (size_t)tcap * bc * 393216;
        bf16* xf   = pong + (size_t)tcap * bc * 393216;

        conv_init_kernel<<<bc * 16, 256, 0, stream>>>(x_all, init_w, init_b, x0,
                                                      dflag, b0, bc);
        {
            const long nn = (long)bc * 262144;
            addnoise_kernel<<<1024, 256, 0, stream>>>(x0, nz_all, nscale, dflag,
                                                      ping, b0, nn);
        }
        conv2(stream, ping, WP + o_pre, nullptr, xsp, 0, 0, bc, 64, 64, 64, 64, 0);

        const long accn = (long)bc * 262144;
        if (tcap > 1) {
            const int Beff = tcap * bc;
            for (int tg = 0; tg < 8; tg += tcap) {
                conv2(stream, xsp, WP + o_tw0 + (long)tg * pt_tw0, nullptr, ping, 0, 1,
                      Beff, 64, 96, 64, 64, 0, nullptr, nullptr, nullptr, nullptr, 0,
                      bc, pt_tw0, bc);
                conv2(stream, ping, WP + o_tw1 + (long)tg * pt_tw1, nullptr, pong, 0, 1,
                      Beff, 96, 96, 64, 64, 0, nullptr, nullptr, nullptr, nullptr, 0,
                      bc, pt_tw1, 0);
                conv2(stream, pong, WP + o_tw2 + (long)tg * pt_tw1, nullptr, ping, 0, 1,
                      Beff, 96, 96, 64, 64, 0, nullptr, nullptr, nullptr, nullptr, 0,
                      bc, pt_tw1, 0);
                conv2(stream, ping, WP + o_tw3 + (long)tg * pt_tw3, nullptr, xf, 0, 0,
                      Beff, 96, 64, 64, 64, 0, nullptr, nullptr, nullptr, nullptr, 0,
                      bc, pt_tw3, 0);
                acc_att_kernel<<<2048, 256, 0, stream>>>(xf, M, tscale, tbias, dflag,
                                                         ACC, bc, tcap, tg,
                                                         tg == 0 ? 1 : 0, accn);
            }
        } else {
            zero_kernel<<<(int)((accn + 255) / 256), 256, 0, stream>>>(ACC, accn);
            for (int t = 0; t < 8; ++t) {
                conv2(stream, xsp,  WP + o_tw0 + (long)t * pt_tw0, nullptr, ping, 0, 1,
                      bc, 64, 96, 64, 64, 0);
                conv2(stream, ping, WP + o_tw1 + (long)t * pt_tw1, nullptr, pong, 0, 1,
                      bc, 96, 96, 64, 64, 0);
                conv2(stream, pong, WP + o_tw2 + (long)t * pt_tw1, nullptr, ping, 0, 1,
                      bc, 96, 96, 64, 64, 0);
                conv2(stream, ping, WP + o_tw3 + (long)t * pt_tw3, nullptr, ACC, 1, 0,
                      bc, 96, 64, 64, 64, 0, nullptr, M, tscale, tbias, t);
            }
        }

        bf16* outc = xsp;
        combine_kernel<<<(int)((accn + 255) / 256), 256, 0, stream>>>(
            x0, ACC, sscale, dflag, outc, accn);

        conv2(stream, outc, WP + o_post, post_b, OUT2, 2, 0, bc, 64, 64, 64, 64, 0,
              outc, nullptr, pscale, nullptr, 0);

        // ---- phase 3: tail ----
        if (S == 256) {
            bf16* a1 = A;
            bf16* a2 = A + (size_t)tc * 1048576;
            bf16* a3 = A + (size_t)tc * 5242880;
            for (int s0 = 0; s0 < bc; s0 += tc) {
                const int cur = (tc < bc - s0) ? tc : (bc - s0);
                const bf16* src_c = OUT2 + (size_t)s0 * 262144;
                float* out_c = outp + (size_t)s0 * 3 * 65536;
                conv2(stream, src_c, WP + o_up1, up1_b, a1, 0, 1, cur, 64, 64, 128, 128, 1);
                conv2(stream, a1,   WP + o_up2, up2_b, a2, 0, 1, cur, 64, 64, 256, 256, 1);
                conv2(stream, a2,   WP + o_hr,  hr_b,  a3, 0, 1, cur, 64, 64, 256, 256, 0);
                conv2(stream, a3,   WP + o_fin, fin_b, out_c, 3, 0, cur, 64, 3, 256, 256, 0);
            }
        } else {
            bf16* a1  = A;
            bf16* a2s = A + 1048576;
            bf16* a3s = a2s + (size_t)(S + 64) * 16384;
            for (int i = 0; i < bc; ++i) {
                const bf16* src_i = OUT2 + (size_t)i * 262144;
                float* out_i = outp + (size_t)i * 3 * 65536;
                conv2(stream, src_i, WP + o_up1, up1_b, a1, 0, 1, 1, 64, 64, 128, 128, 1);
                for (int r0 = 0; r0 < 256; r0 += S) {
                    const int r1 = r0 + S;
                    const int w2a = (r0 - 32 > 0) ? r0 - 32 : 0;
                    const int w2b = (r1 + 32 < 256) ? r1 + 32 : 256;
                    const int w3a = (r0 - 16 > 0) ? r0 - 16 : 0;
                    const int w3b = (r1 + 16 < 256) ? r1 + 16 : 256;
                    conv2w(stream, a1, WP + o_up2, up2_b, a2s, 0, 1,
                           1, 64, 64, 256, 256, 1,
                           0, 128, w2a, w2b - w2a, w2a, w2b - w2a);
                    conv2w(stream, a2s, WP + o_hr, hr_b, a3s, 0, 1,
                           1, 64, 64, 256, 256, 0,
                           w2a, w2b - w2a, w3a, w3b - w3a, w3a, w3b - w3a);
                    conv2w(stream, a3s, WP + o_fin, fin_b, out_i, 3, 0,
                           1, 64, 3, 256, 256, 0,
                           w3a, w3b - w3a, 0, 256, r0, S);
                }
            }
        }
    }
}

// Round 12
// 1193.189 us; speedup vs baseline: 1.1206x; 1.0296x over previous
//
#include <hip/hip_runtime.h>
#include <hip/hip_bf16.h>
#include <math.h>

typedef __hip_bfloat16 bf16;

#define LRELU(v) ((v) >= 0.f ? (v) : 0.2f * (v))

__device__ __forceinline__ float b2f(bf16 v) { return __bfloat162float(v); }
__device__ __forceinline__ bf16 f2b(float v) { return __float2bfloat16(v); }

__device__ __forceinline__ float eload(const void* p, long i, int isf32)
{
    return isf32 ? ((const float*)p)[i] : b2f(((const bf16*)p)[i]);
}

union BfPack { short4 s; bf16 h[4]; };
typedef __attribute__((ext_vector_type(8))) short bfrag_t;   // 8 bf16
typedef __attribute__((ext_vector_type(4))) float ffrag_t;   // 4 f32 acc
union PackU { bfrag_t v; bf16 b[8]; };

// async global->LDS, 16B per lane; LDS dest = wave-uniform base + lane*16
__device__ __forceinline__ void gload_lds16(const bf16* g, bf16* l)
{
    __builtin_amdgcn_global_load_lds(
        (const __attribute__((address_space(1))) void*)g,
        (__attribute__((address_space(3))) void*)l,
        16, 0, 0);
}

// ---------------------------------------------------------------------------
__global__ void dtype_detect_kernel(const void* probe, int n, int* flag)
{
    if (threadIdx.x == 0 && blockIdx.x == 0) {
        const bf16* e = (const bf16*)probe;
        int f32 = 0;
        for (int i = 0; i < n; ++i) {
            const float v = b2f(e[i]);
            if (!(v > -1.0f && v < 1.0f)) f32 = 1;
        }
        *flag = f32;
    }
}

// planar external [b0+b][C][HW] -> NHWC8 bf16 [b][C/8][HW][8]
__global__ void __launch_bounds__(256)
to_nhwc8_kernel(const void* __restrict__ src, const int* __restrict__ dflag,
                bf16* __restrict__ out, int b_off, int C, int HW, long n)
{
    const int ef = dflag[0];
    const int CG = C >> 3;
    for (long i = (long)blockIdx.x * 256 + threadIdx.x; i < n;
         i += (long)gridDim.x * 256) {
        const int c8 = (int)(i & 7);
        long r = i >> 3;
        const int p = (int)(r % HW); r /= HW;
        const int cg = (int)(r % CG);
        const int b = (int)(r / CG);
        out[i] = f2b(eload(src, ((long)(b_off + b) * C + cg * 8 + c8) * HW + p, ef));
    }
}

// ---------------------------------------------------------------------------
// single-launch weight prep: external [t][co][ci][3][3] ->
//   wp[t][cog][cc][tap][...] bf16, A-fragment-ready, zero-pad co.
// Intra-tap layout is LANE-LINEAR for conflict-free ds_read_b128:
//   element A[co][ci] at position co*8 + (ci>>3)*128 + (ci&7)
// so lane l=16q+n (reading co=n, ci=q*8..q*8+7 at offset q*128+n*8) maps to
// slot l -> a wave reads 1024 contiguous bytes (banking floor, 0 conflicts).
// ---------------------------------------------------------------------------
struct WEnt { const void* src; long dst_off; long total; int Cout; int Cin; };
struct WTab { WEnt e[17]; int n; };

__global__ void __launch_bounds__(256)
wprep_all_kernel(WTab tab, const int* __restrict__ dflag, bf16* __restrict__ out)
{
    const int ef = dflag[0];
    for (int k = 0; k < tab.n; ++k) {
        const WEnt E = tab.e[k];
        const int cogs = (E.Cout + 15) >> 4, ccs = E.Cin >> 5;
        const long src_t = (long)E.Cout * E.Cin * 9;
        for (long i = (long)blockIdx.x * 256 + threadIdx.x; i < E.total;
             i += (long)gridDim.x * 256) {
            const int e = (int)(i & 511);
            long r = i >> 9;
            const int tap = (int)(r % 9); r /= 9;
            const int cc = (int)(r % ccs); r /= ccs;
            const int cog = (int)(r % cogs);
            const int t = (int)(r / cogs);
            const int nn = (e >> 3) & 15;            // co (lane-linear layout)
            const int kk = (e >> 7) * 8 + (e & 7);   // ci
            const int co = cog * 16 + nn, ci = cc * 32 + kk;
            float v = 0.f;
            if (co < E.Cout)
                v = eload(E.src, (long)t * src_t + ((long)co * E.Cin + ci) * 9 + tap, ef);
            out[E.dst_off + i] = f2b(v);
        }
    }
}

// ---------------------------------------------------------------------------
// MFMA implicit-GEMM 3x3 conv, NHWC8 src, prepped weights.
// Tile 16x16 px; block handles CPB consecutive cogs (CPB | cogs guaranteed).
// CPB<=3 (48 AGPR) + __launch_bounds__(256,4).
// XCD-aware bijective block swizzle (T1/m204): bid = x*q + min(x,r) + (d>>3).
// Weight fragments staged in LDS (sW) per chunk via global_load_lds width=16
// (coalesced source, LDS dst = wave-uniform base + lane*16); lane-linear
// fragment layout (see wprep) -> conflict-free sW ds_reads. Descriptor
// arrays sized per-CPB (constexpr KW). Src staging: reg path (scattered
// addrs), fused load->ds_write per granule, hoisted descriptors. OOB halo
// zeroed once in prologue. Compute phase is pure LDS+MFMA.
// img_per_t>0: per-image-group weights (merged branches), weight idx = b/img_per_t.
// src_bmod>0: src image index = b % src_bmod (shared-input merged conv).
// dst_kind: 0=NHWC8 bf16 (+act), 1=NHWC8 f32 += (v*es[e]+eb[e])*att,
//           2=NHWC8 bf16 resid + lrelu(v)*es[0], 3=planar f32 (+act).
// ---------------------------------------------------------------------------
template <int CPB>
__global__ void __launch_bounds__(256, 4)
conv_mfma(const bf16* __restrict__ src,
          const bf16* __restrict__ wp,
          const void* __restrict__ bias,
          void* __restrict__ dst, int dst_kind, int act,
          const bf16* __restrict__ resid,
          const float* __restrict__ att,
          const void* __restrict__ es_ptr, const void* __restrict__ eb_ptr,
          int e_idx,
          const int* __restrict__ dflag,
          int B, int Cin, int Cout, int H, int W, int up,
          int cog_blocks,
          int src_row0, int src_rows, int dst_row0, int dst_rows_buf,
          int dst_y0, int dst_rows,
          int img_per_t, long wstride, int src_bmod)
{
    __shared__ __align__(16) bf16 sI[324 * 32];      // 20,736 B
    __shared__ __align__(16) bf16 sW[CPB * 4608];    // 9,216 B per cog

    constexpr int KW = (CPB * 576 + 255) / 256;      // weight granule iters

    const int ef = dflag[0];
    const int ccs  = Cin >> 5;
    const int CGi = Cin >> 3;
    const int CGo = Cout >> 3;
    const int tilesX = W >> 4;
    const int tilesY = dst_rows >> 4;
    const int inW = up ? (W >> 1) : W;

    // ---- XCD-aware bijective remap (m204, simplified chunk-start form) ----
    int bid;
    {
        const unsigned d = blockIdx.x, nwg = gridDim.x;
        const unsigned qq = nwg >> 3, rr = nwg & 7;
        const unsigned x = d & 7;
        bid = (int)(x * qq + (x < rr ? x : rr) + (d >> 3));
    }
    const int cogb = bid % cog_blocks; bid /= cog_blocks;
    const int tx = bid % tilesX; bid /= tilesX;
    const int ty = bid % tilesY;
    const int b  = bid / tilesY;
    const int cog0 = cogb * CPB;
    const int sbi = src_bmod ? (b % src_bmod) : b;
    const bf16* wpb = wp + (img_per_t ? (long)(b / img_per_t) * wstride : 0);

    const int tid = threadIdx.x;
    const int wave = tid >> 6, lane = tid & 63;
    const int n = lane & 15, q = lane >> 4;
    const int yb = dst_y0 + ty * 16, xb = tx * 16;
    const int r0w = wave * 4;

    int cb[3];
#pragma unroll
    for (int d = 0; d < 3; ++d) {
        const int tc = n + d;
        cb[d] = tc * 32 + ((q ^ ((tc >> 1) & 3)) << 3);
    }

    // ---- hoisted src staging descriptors (constant across cc chunks) ----
    unsigned gofs[6];            // element offset at cc=0 (valid iff vmask bit)
    int      lofs[6];            // LDS element offset (swizzled)
    unsigned vmask = 0;
    const unsigned ccstep = (unsigned)((4 * src_rows * inW) << 3);
#pragma unroll
    for (int k = 0; k < 6; ++k) {
        gofs[k] = 0; lofs[k] = 0;
        const int i = tid + k * 256;
        if (i < 1296) {
            const int pc = i % 324;
            const int cig = i / 324;
            const int trow = pc / 18, tcol = pc - trow * 18;
            lofs[k] = pc * 32 + ((cig ^ ((tcol >> 1) & 3)) << 3);
            const int iy = yb + trow - 1, ix = xb + tcol - 1;
            if (iy >= 0 && iy < H && ix >= 0 && ix < W) {
                const int sy = up ? (iy >> 1) : iy;
                const int sx = up ? (ix >> 1) : ix;
                gofs[k] = (unsigned)(((((long)sbi * CGi + cig) * src_rows
                                      + (sy - src_row0)) * inW + sx) << 3);
                vmask |= 1u << k;
            }
        }
    }

    // ---- hoisted weight staging descriptors (divisions once, not per cc) ----
    const long wc_cstride = (long)ccs * 4608;   // per-cog stride in wp
    unsigned wofs[KW];
#pragma unroll
    for (int k = 0; k < KW; ++k) {
        wofs[k] = 0;
        const int g = tid + k * 256;
        if (g < CPB * 576) {
            const int c = g / 576;
            wofs[k] = (unsigned)((long)g * 8 + (long)c * (wc_cstride - 4608));
        }
    }

    // ---- one-time zero of OOB halo slots (never rewritten) ----
    {
        PackU z;
#pragma unroll
        for (int j = 0; j < 8; ++j) z.b[j] = f2b(0.0f);
#pragma unroll
        for (int k = 0; k < 6; ++k)
            if ((tid + k * 256 < 1296) && !(vmask & (1u << k)))
                *(bfrag_t*)&sI[lofs[k]] = z.v;
    }

    ffrag_t acc[CPB][4];
#pragma unroll
    for (int c = 0; c < CPB; ++c)
#pragma unroll
        for (int g = 0; g < 4; ++g) acc[c][g] = (ffrag_t){0.f, 0.f, 0.f, 0.f};

    const bf16* wsrc = wpb + (long)cog0 * ccs * 4608;

    for (int cc = 0; cc < ccs; ++cc) {
        // ---- stage weight fragments: async direct-to-LDS (coalesced src) ----
#pragma unroll
        for (int k = 0; k < KW; ++k) {
            const int g = tid + k * 256;
            if (g < CPB * 576)
                gload_lds16(&wsrc[wofs[k]], &sW[g * 8]);
        }
        wsrc += 4608;
        // ---- stage src chunk cc: fused load->write per granule ----
#pragma unroll
        for (int k = 0; k < 6; ++k) {
            if (vmask & (1u << k)) {
                const bfrag_t v = *(const bfrag_t*)&src[gofs[k]];
                *(bfrag_t*)&sI[lofs[k]] = v;
                gofs[k] += ccstep;
            }
        }
        __syncthreads();

        // ---- compute: pure LDS + MFMA, conflict-free sW reads ----
#pragma unroll
        for (int dx = 0; dx < 3; ++dx) {
            bfrag_t bcol[6];
#pragma unroll
            for (int rr = 0; rr < 6; ++rr)
                bcol[rr] = *(const bfrag_t*)&sI[(r0w + rr) * 18 * 32 + cb[dx]];
#pragma unroll
            for (int c = 0; c < CPB; ++c) {
                const bf16* wbase = &sW[c * 4608 + q * 128 + n * 8];
#pragma unroll
                for (int dy = 0; dy < 3; ++dy) {
                    const bfrag_t a = *(const bfrag_t*)&wbase[(dy * 3 + dx) * 512];
#pragma unroll
                    for (int g = 0; g < 4; ++g)
                        acc[c][g] = __builtin_amdgcn_mfma_f32_16x16x32_bf16(
                            a, bcol[g + dy], acc[c][g], 0, 0, 0);
                }
            }
        }
        __syncthreads();
    }

    // ---- epilogue ----
    const float es  = es_ptr ? eload(es_ptr, e_idx, ef) : 1.0f;
    const float ebv = eb_ptr ? eload(eb_ptr, e_idx, ef) : 0.0f;
    const int x = xb + n;
#pragma unroll
    for (int c = 0; c < CPB; ++c) {
        const int cog = cog0 + c;
        if (dst_kind == 3) {
#pragma unroll
            for (int g = 0; g < 4; ++g) {
                const int y = yb + r0w + g, yr = y - dst_row0;
#pragma unroll
                for (int reg = 0; reg < 4; ++reg) {
                    const int co = cog * 16 + q * 4 + reg;
                    if (co < Cout) {
                        float v = acc[c][g][reg];
                        if (bias) v += eload(bias, co, ef);
                        if (act) v = LRELU(v);
                        ((float*)dst)[(((long)b * Cout + co) * dst_rows_buf + yr) * W + x] = v;
                    }
                }
            }
            continue;
        }
        const int cg = cog * 2 + (q >> 1);
        const int c8 = (q & 1) * 4;
        float bv[4];
#pragma unroll
        for (int reg = 0; reg < 4; ++reg)
            bv[reg] = bias ? eload(bias, cog * 16 + q * 4 + reg, ef) : 0.0f;
#pragma unroll
        for (int g = 0; g < 4; ++g) {
            const int y = yb + r0w + g, yr = y - dst_row0;
            const long base = ((((long)b * CGo + cg) * dst_rows_buf + yr) * W + x) * 8 + c8;
            if (dst_kind == 0) {
                BfPack o;
#pragma unroll
                for (int reg = 0; reg < 4; ++reg) {
                    float v = acc[c][g][reg] + bv[reg];
                    if (act) v = LRELU(v);
                    o.h[reg] = f2b(v);
                }
                *(short4*)&((bf16*)dst)[base] = o.s;
            } else if (dst_kind == 1) {
                const float attv = att[(((long)b * 8 + e_idx) * H + y) * W + x];
                float* dp = (float*)dst + base;
                float4 dv = *(float4*)dp;
                dv.x += ((acc[c][g][0] + bv[0]) * es + ebv) * attv;
                dv.y += ((acc[c][g][1] + bv[1]) * es + ebv) * attv;
                dv.z += ((acc[c][g][2] + bv[2]) * es + ebv) * attv;
                dv.w += ((acc[c][g][3] + bv[3]) * es + ebv) * attv;
                *(float4*)dp = dv;
            } else {
                BfPack rv; rv.s = *(const short4*)&resid[base];
                BfPack o;
#pragma unroll
                for (int reg = 0; reg < 4; ++reg) {
                    const float v = acc[c][g][reg] + bv[reg];
                    o.h[reg] = f2b(b2f(rv.h[reg]) + LRELU(v) * es);
                }
                *(short4*)&((bf16*)dst)[base] = o.s;
            }
        }
    }
}

// ---------------------------------------------------------------------------
// ACC/out = sum_t (xf[t] * tscale[t] + tbias[t]) * att[b,t,:]
// xf: NHWC8 bf16, images [ti*bc + b].
// fin=1 (last t-group): writes outc = x0 + s*ss directly (fused combine),
// ACC untouched. fin=0: accumulates into ACC f32 as before.
// ---------------------------------------------------------------------------
__global__ void __launch_bounds__(256)
acc_att_kernel(const bf16* __restrict__ xf, const float* __restrict__ att,
               const void* __restrict__ ts, const void* __restrict__ tb,
               const int* __restrict__ dflag, float* __restrict__ ACC,
               const bf16* __restrict__ x0, const void* __restrict__ ss,
               bf16* __restrict__ outc,
               int bc, int tcap, int tgrp, int init, int fin, long n)
{
    const int ef = dflag[0];
    const float ssv = fin ? eload(ss, 0, ef) : 0.0f;
    for (long i = (long)blockIdx.x * 256 + threadIdx.x; i < n;
         i += (long)gridDim.x * 256) {
        long r = i >> 3;
        const int p = (int)(r % 4096); r /= 4096;
        r /= 8;                         // skip cg
        const int b = (int)r;
        float s = init ? 0.f : ACC[i];
        for (int ti = 0; ti < tcap; ++ti) {
            const int t = tgrp + ti;
            const float a = att[((long)b * 8 + t) * 4096 + p];
            const float v = b2f(xf[(long)ti * bc * 262144 + i]);
            s += (v * eload(ts, t, ef) + eload(tb, t, ef)) * a;
        }
        if (fin) outc[i] = f2b(b2f(x0[i]) + s * ssv);
        else     ACC[i] = s;
    }
}

// ---------------------------------------------------------------------------
// init conv: planar ext x [b0+b][3][64][64] -> NHWC8 x0, Cout=64.
// FUSED noise add: also writes xs = x0 + ns*noise (replaces addnoise pass).
// ---------------------------------------------------------------------------
__global__ void __launch_bounds__(256)
conv_init_kernel(const void* __restrict__ src, const void* __restrict__ wgt,
                 const void* __restrict__ bias,
                 const void* __restrict__ noise, const void* __restrict__ ns_ptr,
                 bf16* __restrict__ dst, bf16* __restrict__ xs,
                 const int* __restrict__ dflag, int b_off, int B)
{
    __shared__ float slds[3 * 34 * 36];
    __shared__ float wlds[3 * 16 * 12];
    const int ef = dflag[0];

    int bid = blockIdx.x;
    const int coI = bid & 3; bid >>= 2;
    const int tx = bid & 1; bid >>= 1;
    const int ty = bid & 1; bid >>= 1;
    const int b = bid;
    const int co0 = coI * 16;
    const int tid = threadIdx.x;
    const int wave = tid >> 6, lane = tid & 63;
    const int ty4 = lane >> 3, tx4 = lane & 7;
    const int yb = ty * 32, xb = tx * 32;

    for (int i = tid; i < 34 * 34 * 3; i += 256) {
        const int c = i / 1156, p = i % 1156;
        const int row = p / 34, col = p % 34;
        const int iy = yb + row - 1, ix = xb + col - 1;
        float v = 0.f;
        if (iy >= 0 && iy < 64 && ix >= 0 && ix < 64)
            v = eload(src, ((long)(b_off + b) * 3 + c) * 4096 + iy * 64 + ix, ef);
        slds[(c * 34 + row) * 36 + col] = v;
    }
    for (int i = tid; i < 3 * 144; i += 256) {
        const int ci = i / 144, r = i % 144;
        const int co = r / 9, k = r % 9;
        wlds[(ci * 16 + co) * 12 + k] = eload(wgt, ((long)(co0 + co) * 3 + ci) * 9 + k, ef);
    }
    __syncthreads();

    float acc[4][16];
#pragma unroll
    for (int i = 0; i < 4; ++i)
#pragma unroll
        for (int j = 0; j < 16; ++j) acc[i][j] = 0.f;

    for (int ci = 0; ci < 3; ++ci) {
        float in[6][6];
        const float* sp = &slds[(ci * 34 + ty4 * 4) * 36 + tx4 * 4];
#pragma unroll
        for (int r = 0; r < 6; ++r) {
            const float4 v4 = *(const float4*)(sp + r * 36);
            const float2 v2 = *(const float2*)(sp + r * 36 + 4);
            in[r][0] = v4.x; in[r][1] = v4.y; in[r][2] = v4.z; in[r][3] = v4.w;
            in[r][4] = v2.x; in[r][5] = v2.y;
        }
#pragma unroll
        for (int cc = 0; cc < 4; ++cc) {
            const float* wp = &wlds[(ci * 16 + wave * 4 + cc) * 12];
            const float4 wa = *(const float4*)wp;
            const float4 wb = *(const float4*)(wp + 4);
            const float w8 = wp[8];
#pragma unroll
            for (int r = 0; r < 4; ++r)
#pragma unroll
                for (int c = 0; c < 4; ++c)
                    acc[cc][r * 4 + c] += in[r][c] * wa.x + in[r][c+1] * wa.y + in[r][c+2] * wa.z
                        + in[r+1][c] * wa.w + in[r+1][c+1] * wb.x + in[r+1][c+2] * wb.y
                        + in[r+2][c] * wb.z + in[r+2][c+1] * wb.w + in[r+2][c+2] * w8;
        }
    }

    const int cg = coI * 2 + (wave >> 1);
    const int c8 = (wave & 1) * 4;
    const float ns = eload(ns_ptr, 0, ef);
    float bv[4];
#pragma unroll
    for (int cc = 0; cc < 4; ++cc)
        bv[cc] = bias ? eload(bias, co0 + wave * 4 + cc, ef) : 0.0f;
#pragma unroll
    for (int r = 0; r < 4; ++r) {
        const int y = yb + ty4 * 4 + r;
#pragma unroll
        for (int c = 0; c < 4; ++c) {
            const int x = xb + tx4 * 4 + c;
            BfPack o, o2;
#pragma unroll
            for (int cc = 0; cc < 4; ++cc) {
                const float v = acc[cc][r * 4 + c] + bv[cc];
                o.h[cc] = f2b(v);
                const int ch = co0 + wave * 4 + cc;
                const float nz = eload(noise,
                    ((long)(b_off + b) * 64 + ch) * 4096 + y * 64 + x, ef);
                o2.h[cc] = f2b(v + ns * nz);
            }
            const long idx = ((((long)b * 8 + cg) * 64 + y) * 64 + x) * 8 + c8;
            *(short4*)&dst[idx] = o.s;
            *(short4*)&xs[idx]  = o2.s;
        }
    }
}

// ---------------------------------------------------------------------------
__global__ void __launch_bounds__(256)
gn_silu_kernel(bf16* __restrict__ d, const void* __restrict__ g,
               const void* __restrict__ be, const int* __restrict__ dflag,
               int C, int gsize, int HW)
{
    const int ef = dflag[0];
    const int groups = C / gsize;
    const int blk = blockIdx.x;
    const int b  = blk / groups;
    const int gr = blk % groups;
    const long base = ((long)b * (C >> 3) + (long)gr * (gsize >> 3)) * HW * 8;
    const int N = gsize * HW;

    float s = 0.0f, ss = 0.0f;
    for (int i = threadIdx.x; i < N; i += 256) {
        const float v = b2f(d[base + i]);
        s += v; ss += v * v;
    }
    __shared__ float rs[256], rss[256];
    rs[threadIdx.x] = s; rss[threadIdx.x] = ss;
    __syncthreads();
    for (int o = 128; o > 0; o >>= 1) {
        if (threadIdx.x < o) {
            rs[threadIdx.x]  += rs[threadIdx.x + o];
            rss[threadIdx.x] += rss[threadIdx.x + o];
        }
        __syncthreads();
    }
    __shared__ float mean_s, inv_s;
    if (threadIdx.x == 0) {
        const float mean = rs[0] / (float)N;
        const float var  = rss[0] / (float)N - mean * mean;
        mean_s = mean; inv_s = rsqrtf(var + 1e-5f);
    }
    __syncthreads();
    const float mean = mean_s, inv = inv_s;
    for (int i = threadIdx.x; i < N; i += 256) {
        const int c = gr * gsize + (i / (HW * 8)) * 8 + (i & 7);
        const float v  = b2f(d[base + i]);
        const float xn = (v - mean) * inv * eload(g, c, ef) + eload(be, c, ef);
        d[base + i] = f2b(xn / (1.0f + expf(-xn)));
    }
}

__global__ void __launch_bounds__(256)
softmax_t_kernel(float* __restrict__ m, int BHW, int HW, float invtemp)
{
    const int i = blockIdx.x * 256 + threadIdx.x;
    if (i >= BHW) return;
    const int b = i / HW;
    const int p = i % HW;
    const long base = (long)b * 8 * HW + p;
    float v[8];
    float mx = -1e30f;
#pragma unroll
    for (int t = 0; t < 8; ++t) {
        v[t] = m[base + (long)t * HW] * invtemp;
        mx = fmaxf(mx, v[t]);
    }
    float s = 0.0f;
#pragma unroll
    for (int t = 0; t < 8; ++t) { v[t] = expf(v[t] - mx); s += v[t]; }
    const float r = 1.0f / s;
#pragma unroll
    for (int t = 0; t < 8; ++t) m[base + (long)t * HW] = v[t] * r;
}

__global__ void __launch_bounds__(256)
combine_kernel(const bf16* __restrict__ x0, const float* __restrict__ acc,
               const void* __restrict__ ss, const int* __restrict__ dflag,
               bf16* __restrict__ out, long n)
{
    const long i = (long)blockIdx.x * 256 + threadIdx.x;
    if (i < n) out[i] = f2b(b2f(x0[i]) + acc[i] * eload(ss, 0, dflag[0]));
}

__global__ void __launch_bounds__(256)
zero_kernel(float* __restrict__ p, long n)
{
    const long i = (long)blockIdx.x * 256 + threadIdx.x;
    if (i < n) p[i] = 0.0f;
}

// ---------------------------------------------------------------------------
static const int* g_dflag;

static void conv2w(hipStream_t st, const bf16* src, const bf16* wp,
                   const void* bias, void* dst, int dst_kind, int act,
                   int B, int Cin, int Cout, int H, int W, int up,
                   int src_row0, int src_rows, int dst_row0, int dst_rows_buf,
                   int dst_y0, int dst_rows,
                   const bf16* resid = nullptr, const float* att = nullptr,
                   const void* es = nullptr, const void* eb = nullptr, int eidx = 0,
                   int img_per_t = 0, long wstride = 0, int src_bmod = 0)
{
    const int cogs = (Cout + 15) >> 4;
    const int spatial = B * (dst_rows >> 4) * (W >> 4);
    // CPB: largest divisor of cogs (<=3, 48 AGPR cap) whose block count
    // fills residency (>=1024); else 1.
    static const int cands[3] = {3, 2, 1};
    int cpb = 1;
    for (int k = 0; k < 3; ++k) {
        const int c = cands[k];
        if (cogs % c) continue;
        if ((long)spatial * (cogs / c) >= 1024) { cpb = c; break; }
        if (c == 1) cpb = 1;   // tiny spatial: max blocks, L2 eats restaging
    }
    const int cogb = cogs / cpb;
    const int blocks = spatial * cogb;
#define LAUNCH(CP) conv_mfma<CP><<<blocks, 256, 0, st>>>( \
        src, wp, bias, dst, dst_kind, act, resid, att, es, eb, eidx, g_dflag, \
        B, Cin, Cout, H, W, up, cogb, \
        src_row0, src_rows, dst_row0, dst_rows_buf, dst_y0, dst_rows, \
        img_per_t, wstride, src_bmod)
    switch (cpb) {
        case 3: LAUNCH(3); break;
        case 2: LAUNCH(2); break;
        default: LAUNCH(1); break;
    }
#undef LAUNCH
}

static void conv2(hipStream_t st, const bf16* src, const bf16* wp,
                  const void* bias, void* dst, int dst_kind, int act,
                  int B, int Cin, int Cout, int H, int W, int up,
                  const bf16* resid = nullptr, const float* att = nullptr,
                  const void* es = nullptr, const void* eb = nullptr, int eidx = 0,
                  int img_per_t = 0, long wstride = 0, int src_bmod = 0)
{
    conv2w(st, src, wp, bias, dst, dst_kind, act, B, Cin, Cout, H, W, up,
           0, up ? (H >> 1) : H, 0, H, 0, H, resid, att, es, eb, eidx,
           img_per_t, wstride, src_bmod);
}

static long wp_elems(int T, int Cout, int Cin)
{
    return (long)T * ((Cout + 15) / 16) * (Cin / 32) * 9 * 512;
}

extern "C" void kernel_launch(void* const* d_in, const int* in_sizes, int n_in,
                              void* d_out, int out_size, void* d_ws, size_t ws_size,
                              hipStream_t stream)
{
    const void* x_all   = d_in[0];
    const void* sp_all  = d_in[1];
    const void* nz_all  = d_in[2];
    const void* init_w  = d_in[3];
    const void* init_b  = d_in[4];
    const void* pre_w   = d_in[5];
    const void* tw0     = d_in[6];
    const void* tw1     = d_in[7];
    const void* tw2     = d_in[8];
    const void* tw3     = d_in[9];
    const void* tscale  = d_in[10];
    const void* tbias   = d_in[11];
    const void* nscale  = d_in[12];
    const void* sscale  = d_in[13];
    const void* pscale  = d_in[14];
    const void* post_w  = d_in[15];
    const void* post_b  = d_in[16];
    const void* m1_w    = d_in[17];
    const void* m1_b    = d_in[18];
    const void* m1_g    = d_in[19];
    const void* m1_be   = d_in[20];
    const void* m2_w    = d_in[21];
    const void* m2_g    = d_in[22];
    const void* m2_be   = d_in[23];
    const void* u1a_w   = d_in[24];
    const void* u1b_w   = d_in[25];
    const void* u1b_g   = d_in[26];
    const void* u1b_be  = d_in[27];
    const void* u2a_w   = d_in[28];
    const void* u2b_w   = d_in[29];
    const void* u2b_g   = d_in[30];
    const void* u2b_be  = d_in[31];
    const void* mf_w    = d_in[32];
    const void* up1_w   = d_in[33];
    const void* up1_b   = d_in[34];
    const void* up2_w   = d_in[35];
    const void* up2_b   = d_in[36];
    const void* hr_w    = d_in[37];
    const void* hr_b    = d_in[38];
    const void* fin_w   = d_in[39];
    const void* fin_b   = d_in[40];
    (void)in_sizes; (void)n_in; (void)out_size;

    char* wsb = (char*)d_ws;
    int* dflag = (int*)wsb;
    g_dflag = dflag;
    dtype_detect_kernel<<<1, 64, 0, stream>>>(tw1, 128, dflag);

    // ---- prepped-weight region ----
    bf16* WP = (bf16*)(wsb + 256);
    long off = 0;
    WTab tab; tab.n = 0;
    auto alloc = [&](const void* w, int T, int Cout, int Cin) {
        long o = off;
        long tot = wp_elems(T, Cout, Cin);
        tab.e[tab.n++] = WEnt{w, o, tot, Cout, Cin};
        off += tot;
        return o;
    };
    const long o_m1  = alloc(m1_w, 1, 256, 256);
    const long o_m2  = alloc(m2_w, 1, 256, 256);
    const long o_u1a = alloc(u1a_w, 1, 128, 256);
    const long o_u1b = alloc(u1b_w, 1, 128, 128);
    const long o_u2a = alloc(u2a_w, 1, 64, 128);
    const long o_u2b = alloc(u2b_w, 1, 64, 64);
    const long o_mf  = alloc(mf_w, 1, 8, 64);
    const long o_pre = alloc(pre_w, 1, 64, 64);
    const long o_tw0 = alloc(tw0, 8, 96, 64);
    const long o_tw1 = alloc(tw1, 8, 96, 96);
    const long o_tw2 = alloc(tw2, 8, 96, 96);
    const long o_tw3 = alloc(tw3, 8, 64, 96);
    const long o_post = alloc(post_w, 1, 64, 64);
    const long o_up1 = alloc(up1_w, 1, 64, 64);
    const long o_up2 = alloc(up2_w, 1, 64, 64);
    const long o_hr  = alloc(hr_w, 1, 64, 64);
    const long o_fin = alloc(fin_w, 1, 3, 64);
    const long wp_total = off;
    const size_t wp_bytes = (size_t)((wp_total * 2 + 255) & ~255L);

    wprep_all_kernel<<<1024, 256, 0, stream>>>(tab, dflag, WP);

    const long pt_tw0 = wp_elems(1, 96, 64), pt_tw1 = wp_elems(1, 96, 96);
    const long pt_tw3 = wp_elems(1, 64, 96);

    // ---- schedule: batch chunk bc, branch merge tcap, tail strip S ----
    int bc = 1, tcap = 1, S = 16, tc = 1;
    bool found = false;
    for (int c = 16; c >= 1 && !found; c >>= 1) {
        const size_t fixed = 256u + wp_bytes + (size_t)c * 1703936u;
        if (ws_size < fixed) continue;
        const size_t avail = ws_size - fixed;
        const size_t p1 = (size_t)c * 2228224u;                   // phase1
        auto p2 = [&](int t) -> size_t {
            if (t == 1) return (size_t)c * 2621440u;              // no xf
            return (size_t)c * 2u * (524288u + (size_t)t * 1048576u);
        };
        size_t need = p1;
        if (p2(1) > need) need = p2(1);
        if (need < 6291456u) need = 6291456u;
        if (avail < need) continue;
        bc = c; found = true;
        for (int t = 8; t >= 1; t >>= 1)
            if (p2(t) <= avail && p1 <= avail) { tcap = t; break; }
        if (avail >= 18874368u) {
            S = 256; tc = (int)(avail / 18874368u); if (tc > c) tc = c;
        } else if (avail >= 9437184u) S = 64;
        else if (avail >= 7340032u)  S = 32;
        else S = 16;
    }

    char* dyn = wsb + 256 + wp_bytes;
    float* M    = (float*)dyn;                                   // bc*32768 f32
    float* ACC  = (float*)(dyn + (size_t)bc * 131072u);          // bc*262144 f32
    bf16*  OUT2 = (bf16*)(dyn + (size_t)bc * 1179648u);          // bc*262144 bf16
    bf16*  A    = (bf16*)(dyn + (size_t)bc * 1703936u);          // arena

    for (int b0 = 0; b0 < 16; b0 += bc) {
        float* outp = (float*)d_out + (size_t)b0 * 3 * 65536;

        // ---- phase 1: multiplexer ----
        bf16* SP8 = A;
        bf16* f1 = A + (size_t)bc * 65536;
        bf16* f2 = A + (size_t)bc * 131072;
        bf16* g1 = A + (size_t)bc * 196608;
        bf16* g2 = A + (size_t)bc * 327680;
        bf16* h1 = A + (size_t)bc * 458752;
        bf16* h2 = A + (size_t)bc * 720896;

        {
            const long nn = (long)bc * 65536;
            to_nhwc8_kernel<<<1024, 256, 0, stream>>>(sp_all, dflag, SP8, b0, 256, 256, nn);
        }
        conv2(stream, SP8, WP + o_m1, m1_b, f1, 0, 0, bc, 256, 256, 16, 16, 0);
        gn_silu_kernel<<<bc * 8, 256, 0, stream>>>(f1, m1_g, m1_be, dflag, 256, 32, 256);
        conv2(stream, f1, WP + o_m2, nullptr, f2, 0, 0, bc, 256, 256, 16, 16, 0);
        gn_silu_kernel<<<bc * 8, 256, 0, stream>>>(f2, m2_g, m2_be, dflag, 256, 32, 256);
        conv2(stream, f2, WP + o_u1a, nullptr, g1, 0, 0, bc, 256, 128, 32, 32, 1);
        conv2(stream, g1, WP + o_u1b, nullptr, g2, 0, 0, bc, 128, 128, 32, 32, 0);
        gn_silu_kernel<<<bc * 8, 256, 0, stream>>>(g2, u1b_g, u1b_be, dflag, 128, 16, 1024);
        conv2(stream, g2, WP + o_u2a, nullptr, h1, 0, 0, bc, 128, 64, 64, 64, 1);
        conv2(stream, h1, WP + o_u2b, nullptr, h2, 0, 0, bc, 64, 64, 64, 64, 0);
        gn_silu_kernel<<<bc * 8, 256, 0, stream>>>(h2, u2b_g, u2b_be, dflag, 64, 8, 4096);
        conv2(stream, h2, WP + o_mf, nullptr, M, 3, 0, bc, 64, 8, 64, 64, 0);
        softmax_t_kernel<<<(bc * 4096 + 255) / 256, 256, 0, stream>>>(
            M, bc * 4096, 4096, 1.0f / 20.0f);

        // ---- phase 2: stem + branches ----
        bf16* x0   = A;
        bf16* xsp  = A + (size_t)bc * 262144;
        bf16* ping = A + (size_t)bc * 524288;
        bf16* pong = ping + (size_t)tcap * bc * 393216;
        bf16* xf   = pong + (size_t)tcap * bc * 393216;

        // fused: conv_init writes x0 AND xs(=ping) = x0 + ns*noise
        conv_init_kernel<<<bc * 16, 256, 0, stream>>>(x_all, init_w, init_b,
                                                      nz_all, nscale,
                                                      x0, ping, dflag, b0, bc);
        conv2(stream, ping, WP + o_pre, nullptr, xsp, 0, 0, bc, 64, 64, 64, 64, 0);

        const long accn = (long)bc * 262144;
        if (tcap > 1) {
            const int Beff = tcap * bc;
            for (int tg = 0; tg < 8; tg += tcap) {
                conv2(stream, xsp, WP + o_tw0 + (long)tg * pt_tw0, nullptr, ping, 0, 1,
                      Beff, 64, 96, 64, 64, 0, nullptr, nullptr, nullptr, nullptr, 0,
                      bc, pt_tw0, bc);
                conv2(stream, ping, WP + o_tw1 + (long)tg * pt_tw1, nullptr, pong, 0, 1,
                      Beff, 96, 96, 64, 64, 0, nullptr, nullptr, nullptr, nullptr, 0,
                      bc, pt_tw1, 0);
                conv2(stream, pong, WP + o_tw2 + (long)tg * pt_tw1, nullptr, ping, 0, 1,
                      Beff, 96, 96, 64, 64, 0, nullptr, nullptr, nullptr, nullptr, 0,
                      bc, pt_tw1, 0);
                conv2(stream, ping, WP + o_tw3 + (long)tg * pt_tw3, nullptr, xf, 0, 0,
                      Beff, 96, 64, 64, 64, 0, nullptr, nullptr, nullptr, nullptr, 0,
                      bc, pt_tw3, 0);
                // fused: final group writes outc = x0 + s*ss directly
                acc_att_kernel<<<2048, 256, 0, stream>>>(
                    xf, M, tscale, tbias, dflag, ACC,
                    x0, sscale, xsp /*outc*/,
                    bc, tcap, tg, tg == 0 ? 1 : 0,
                    (tg + tcap == 8) ? 1 : 0, accn);
            }
        } else {
            zero_kernel<<<(int)((accn + 255) / 256), 256, 0, stream>>>(ACC, accn);
            for (int t = 0; t < 8; ++t) {
                conv2(stream, xsp,  WP + o_tw0 + (long)t * pt_tw0, nullptr, ping, 0, 1,
                      bc, 64, 96, 64, 64, 0);
                conv2(stream, ping, WP + o_tw1 + (long)t * pt_tw1, nullptr, pong, 0, 1,
                      bc, 96, 96, 64, 64, 0);
                conv2(stream, pong, WP + o_tw2 + (long)t * pt_tw1, nullptr, ping, 0, 1,
                      bc, 96, 96, 64, 64, 0);
                conv2(stream, ping, WP + o_tw3 + (long)t * pt_tw3, nullptr, ACC, 1, 0,
                      bc, 96, 64, 64, 64, 0, nullptr, M, tscale, tbias, t);
            }
            combine_kernel<<<(int)((accn + 255) / 256), 256, 0, stream>>>(
                x0, ACC, sscale, dflag, xsp, accn);
        }

        bf16* outc = xsp;
        conv2(stream, outc, WP + o_post, post_b, OUT2, 2, 0, bc, 64, 64, 64, 64, 0,
              outc, nullptr, pscale, nullptr, 0);

        // ---- phase 3: tail ----
        if (S == 256) {
            bf16* a1 = A;
            bf16* a2 = A + (size_t)tc * 1048576;
            bf16* a3 = A + (size_t)tc * 5242880;
            for (int s0 = 0; s0 < bc; s0 += tc) {
                const int cur = (tc < bc - s0) ? tc : (bc - s0);
                const bf16* src_c = OUT2 + (size_t)s0 * 262144;
                float* out_c = outp + (size_t)s0 * 3 * 65536;
                conv2(stream, src_c, WP + o_up1, up1_b, a1, 0, 1, cur, 64, 64, 128, 128, 1);
                conv2(stream, a1,   WP + o_up2, up2_b, a2, 0, 1, cur, 64, 64, 256, 256, 1);
                conv2(stream, a2,   WP + o_hr,  hr_b,  a3, 0, 1, cur, 64, 64, 256, 256, 0);
                conv2(stream, a3,   WP + o_fin, fin_b, out_c, 3, 0, cur, 64, 3, 256, 256, 0);
            }
        } else {
            bf16* a1  = A;
            bf16* a2s = A + 1048576;
            bf16* a3s = a2s + (size_t)(S + 64) * 16384;
            for (int i = 0; i < bc; ++i) {
                const bf16* src_i = OUT2 + (size_t)i * 262144;
                float* out_i = outp + (size_t)i * 3 * 65536;
                conv2(stream, src_i, WP + o_up1, up1_b, a1, 0, 1, 1, 64, 64, 128, 128, 1);
                for (int r0 = 0; r0 < 256; r0 += S) {
                    const int r1 = r0 + S;
                    const int w2a = (r0 - 32 > 0) ? r0 - 32 : 0;
                    const int w2b = (r1 + 32 < 256) ? r1 + 32 : 256;
                    const int w3a = (r0 - 16 > 0) ? r0 - 16 : 0;
                    const int w3b = (r1 + 16 < 256) ? r1 + 16 : 256;
                    conv2w(stream, a1, WP + o_up2, up2_b, a2s, 0, 1,
                           1, 64, 64, 256, 256, 1,
                           0, 128, w2a, w2b - w2a, w2a, w2b - w2a);
                    conv2w(stream, a2s, WP + o_hr, hr_b, a3s, 0, 1,
                           1, 64, 64, 256, 256, 0,
                           w2a, w2b - w2a, w3a, w3b - w3a, w3a, w3b - w3a);
                    conv2w(stream, a3s, WP + o_fin, fin_b, out_i, 3, 0,
                           1, 64, 3, 256, 256, 0,
                           w3a, w3b - w3a, 0, 256, r0, S);
                }
            }
        }
    }
}